// Round 7
// baseline (443.433 us; speedup 1.0000x reference)
//
#include <hip/hip_runtime.h>
#include <hip/hip_bf16.h>
#include <math.h>

#define NN   50000
#define EE   1600000
#define ETOT (EE + NN)
#define HID  128
#define INF_ 64
#define OUTF 64

// bucketed CSR build
#define NBK  1024   // buckets (contiguous dst ranges)
#define NPB  49     // nodes per bucket (1024*49 = 50176 >= NN)
#define CAP  3072   // per-bucket capacity; mean ~1617, 1.9x headroom
#define BBLK 128    // blocks for k_bucket
#define CHUNK ((ETOT + BBLK - 1) / BBLK)   // 12891 edges per block

#define PADX 72     // xbf row stride (ushorts), 144 B (16B-aligned)
#define PADH 136    // hbf row stride (ushorts), 272 B (16B-aligned)

typedef short  short8  __attribute__((ext_vector_type(8)));
typedef float  floatx4 __attribute__((ext_vector_type(4)));

__device__ __forceinline__ ushort f2b(float f) {
    __hip_bfloat16 h = __float2bfloat16(f);
    return *reinterpret_cast<ushort*>(&h);
}

// fast tanh-gelu: gelu(x) = x * t/(t+1), t = exp(2u), u = 0.79788456*(x+0.044715x^3)
__device__ __forceinline__ float gelu_f(float x) {
    float x2 = x * x;
    float u  = 0.7978845608f * fmaf(0.044715f * x2, x, x);
    u = fminf(u, 40.f);                 // overflow guard (LN'd inputs never get here)
    float t = __expf(2.f * u);
    return x * t / (t + 1.f);
}

// ---------------- CSR build (bucketed counting sort) ----------------

__global__ void k_zero(int* bcur) {
    int i = blockIdx.x * 256 + threadIdx.x;
    if (i < NBK) bcur[i] = 0;
}

__global__ __launch_bounds__(1024) void k_bucket(const int* __restrict__ ei,
                                                 int* bcur, int* __restrict__ tmp) {
    __shared__ unsigned sortedv[CHUNK];
    __shared__ int hist[NBK], gbase[NBK], loff[NBK], lcur[NBK];
    int t = threadIdx.x;
    int lo = blockIdx.x * CHUNK;
    int hi = min(lo + CHUNK, ETOT);
    int bsize = hi - lo;
    hist[t] = 0;
    __syncthreads();
    for (int i = lo + t; i < hi; i += 1024) {
        int d = (i < EE) ? ei[EE + i] : i - EE;
        atomicAdd(&hist[d / NPB], 1);
    }
    __syncthreads();
    {
        int c = hist[t];
        gbase[t] = (c > 0) ? atomicAdd(&bcur[t], c) : 0;
        loff[t] = c;
    }
    __syncthreads();
    for (int d = 1; d < NBK; d <<= 1) {
        int v = (t >= d) ? loff[t - d] : 0;
        __syncthreads();
        loff[t] += v;
        __syncthreads();
    }
    {
        int ex = loff[t] - hist[t];
        __syncthreads();
        loff[t] = ex;
        lcur[t] = ex;
    }
    __syncthreads();
    for (int i = lo + t; i < hi; i += 1024) {
        unsigned s, d;
        if (i < EE) { s = (unsigned)ei[i]; d = (unsigned)ei[EE + i]; }
        else        { s = d = (unsigned)(i - EE); }
        unsigned b = d / NPB;
        int p = atomicAdd(&lcur[b], 1);
        sortedv[p] = (b << 22) | (s << 6) | (d - b * NPB);
    }
    __syncthreads();
    for (int i = t; i < bsize; i += 1024) {
        unsigned v = sortedv[i];
        unsigned b = v >> 22;
        int pp = gbase[b] + i - loff[b];
        if (pp < CAP) tmp[b * CAP + pp] = (int)(v & 0x3FFFFFu);
    }
}

__global__ __launch_bounds__(1024) void k_bscan(const int* __restrict__ bcur,
                                                int* __restrict__ bstart,
                                                int* __restrict__ off) {
    __shared__ int s[NBK];
    int t = threadIdx.x;
    int v0 = bcur[t];
    s[t] = v0;
    __syncthreads();
    for (int d = 1; d < NBK; d <<= 1) {
        int v = (t >= d) ? s[t - d] : 0;
        __syncthreads();
        s[t] += v;
        __syncthreads();
    }
    bstart[t] = s[t] - v0;
    if (t == 0) off[NN] = ETOT;
}

__global__ __launch_bounds__(256) void k_bucket2csr(const int* __restrict__ tmp,
                                                    const int* __restrict__ bcur,
                                                    const int* __restrict__ bstart,
                                                    int* __restrict__ off,
                                                    int* __restrict__ csr,
                                                    int* __restrict__ dstid) {
    __shared__ int sE[CAP];
    __shared__ int lcnt[NPB];
    __shared__ int loff[NPB];
    int b = blockIdx.x, t = threadIdx.x;
    int n0    = b * NPB;
    int bsize = min(bcur[b], CAP);
    int base  = bstart[b];
    if (t < NPB) lcnt[t] = 0;
    for (int i = t; i < bsize; i += 256) sE[i] = tmp[b * CAP + i];
    __syncthreads();
    for (int i = t; i < bsize; i += 256) atomicAdd(&lcnt[sE[i] & 63], 1);
    __syncthreads();
    if (t == 0) {
        int run = 0;
        for (int j = 0; j < NPB; ++j) { loff[j] = run; run += lcnt[j]; }
    }
    __syncthreads();
    if (t < NPB) {
        if (n0 + t < NN) off[n0 + t] = base + loff[t];
        lcnt[t] = loff[t];
    }
    __syncthreads();
    for (int i = t; i < bsize; i += 256) {
        int v   = sE[i];
        int d   = v & 63;
        int pos = base + atomicAdd(&lcnt[d], 1);
        csr[pos]   = v >> 6;
        dstid[pos] = n0 + d;
    }
}

// ---------------- weight packing into MFMA B-fragment order ----------------
// frag index (T*kst + s)*64 + l holds B[k = s*32 + (l>>4)*8 + j][n = T*16 + (l&15)], j=0..7

__global__ void k_pack(const float* __restrict__ W, ushort* __restrict__ dst,
                       int K, int N) {
    int tid = blockIdx.x * 256 + threadIdx.x;
    int kst = K >> 5;
    int total = (N >> 4) * kst * 64;
    if (tid >= total) return;
    int l = tid & 63;
    int s = (tid >> 6) % kst;
    int T = tid / (kst * 64);
    int m = l & 15, q = l >> 4;
    ushort o[8];
    #pragma unroll
    for (int j = 0; j < 8; ++j)
        o[j] = f2b(W[(s * 32 + q * 8 + j) * N + T * 16 + m]);
    uint4 pk;
    pk.x = (unsigned)o[0] | ((unsigned)o[1] << 16);
    pk.y = (unsigned)o[2] | ((unsigned)o[3] << 16);
    pk.z = (unsigned)o[4] | ((unsigned)o[5] << 16);
    pk.w = (unsigned)o[6] | ((unsigned)o[7] << 16);
    reinterpret_cast<uint4*>(dst)[tid] = pk;
}

// ------- MFMA fused: x@w_in -> +bias -> LN -> GELU -> @W -> hWb + scores -------

__global__ __launch_bounds__(128) void k_infeat(const float* __restrict__ x,
                                                const ushort* __restrict__ Bp1,
                                                const float* __restrict__ bin,
                                                const float* __restrict__ g,
                                                const float* __restrict__ be,
                                                const ushort* __restrict__ Bp2,
                                                const float* __restrict__ asrc,
                                                const float* __restrict__ adst,
                                                ushort* __restrict__ hWb,
                                                float* __restrict__ esrc,
                                                float* __restrict__ edst) {
    __shared__ ushort xbf[2][16 * PADX];
    __shared__ ushort hbf[2][16 * PADH];
    int t = threadIdx.x, w = t >> 6, l = t & 63;
    int m = l & 15, q = l >> 4;
    int n0w = blockIdx.x * 32 + w * 16;
    bool active = (n0w < NN);
    int nb = active ? n0w : 0;

    const float4* x4 = reinterpret_cast<const float4*>(x) + (size_t)nb * 16;
    #pragma unroll
    for (int i = 0; i < 4; ++i) {
        int f4 = l + 64 * i;
        int node = f4 >> 4, c4 = f4 & 15;
        float4 v = x4[f4];
        ushort4 pk = { f2b(v.x), f2b(v.y), f2b(v.z), f2b(v.w) };
        *reinterpret_cast<ushort4*>(&xbf[w][node * PADX + c4 * 4]) = pk;
    }
    __syncthreads();

    const short8* B1 = reinterpret_cast<const short8*>(Bp1);
    floatx4 acc1[8];
    #pragma unroll
    for (int T = 0; T < 8; ++T) acc1[T] = (floatx4){0.f, 0.f, 0.f, 0.f};
    #pragma unroll
    for (int s = 0; s < 2; ++s) {
        short8 a = *reinterpret_cast<const short8*>(&xbf[w][m * PADX + s * 32 + q * 8]);
        #pragma unroll
        for (int T = 0; T < 8; ++T) {
            short8 b = B1[(T * 2 + s) * 64 + l];
            acc1[T] = __builtin_amdgcn_mfma_f32_16x16x32_bf16(a, b, acc1[T], 0, 0, 0);
        }
    }

    float bc[8], gc[8], bec[8];
    #pragma unroll
    for (int T = 0; T < 8; ++T) {
        int c = T * 16 + m;
        bc[T] = bin[c]; gc[T] = g[c]; bec[T] = be[c];
    }
    #pragma unroll
    for (int j = 0; j < 4; ++j) {
        float s1 = 0.f, s2 = 0.f;
        #pragma unroll
        for (int T = 0; T < 8; ++T) {
            float v = acc1[T][j] + bc[T];
            s1 += v; s2 = fmaf(v, v, s2);
        }
        #pragma unroll
        for (int mk = 1; mk < 16; mk <<= 1) {
            s1 += __shfl_xor(s1, mk, 64);
            s2 += __shfl_xor(s2, mk, 64);
        }
        float mu = s1 * (1.f / 128.f);
        float var = s2 * (1.f / 128.f) - mu * mu;
        float rs = rsqrtf(var + 1e-5f);
        #pragma unroll
        for (int T = 0; T < 8; ++T) {
            float v = acc1[T][j] + bc[T];
            float y = (v - mu) * rs * gc[T] + bec[T];
            hbf[w][(q * 4 + j) * PADH + T * 16 + m] = f2b(gelu_f(y));
        }
    }
    __syncthreads();

    const short8* B2 = reinterpret_cast<const short8*>(Bp2);
    floatx4 acc2[8];
    #pragma unroll
    for (int T = 0; T < 8; ++T) acc2[T] = (floatx4){0.f, 0.f, 0.f, 0.f};
    #pragma unroll
    for (int s = 0; s < 4; ++s) {
        short8 a = *reinterpret_cast<const short8*>(&hbf[w][m * PADH + s * 32 + q * 8]);
        #pragma unroll
        for (int T = 0; T < 8; ++T) {
            short8 b = B2[(T * 4 + s) * 64 + l];
            acc2[T] = __builtin_amdgcn_mfma_f32_16x16x32_bf16(a, b, acc2[T], 0, 0, 0);
        }
    }

    float as_[8], ad_[8];
    #pragma unroll
    for (int T = 0; T < 8; ++T) {
        int c = T * 16 + m;
        as_[T] = asrc[c]; ad_[T] = adst[c];
    }
    if (active) {
        #pragma unroll
        for (int j = 0; j < 4; ++j)
            #pragma unroll
            for (int T = 0; T < 8; ++T)
                hWb[(size_t)(n0w + q * 4 + j) * HID + T * 16 + m] = f2b(acc2[T][j]);
    }
    #pragma unroll
    for (int j = 0; j < 4; ++j) {
        #pragma unroll
        for (int h = 0; h < 4; ++h) {
            float v1 = fmaf(acc2[2 * h][j], as_[2 * h], acc2[2 * h + 1][j] * as_[2 * h + 1]);
            float v2 = fmaf(acc2[2 * h][j], ad_[2 * h], acc2[2 * h + 1][j] * ad_[2 * h + 1]);
            #pragma unroll
            for (int mk = 1; mk < 16; mk <<= 1) {
                v1 += __shfl_xor(v1, mk, 64);
                v2 += __shfl_xor(v2, mk, 64);
            }
            if (m == 0 && active) {
                esrc[(n0w + q * 4 + j) * 4 + h] = v1;
                edst[(n0w + q * 4 + j) * 4 + h] = v2;
            }
        }
    }
}

// ------- MFMA fused layer-2: LN(gout) -> GELU -> @W2 -> hWb + scores -------

__global__ __launch_bounds__(128) void k_feat(const float* __restrict__ hin,
                                              const float* __restrict__ g,
                                              const float* __restrict__ be,
                                              const ushort* __restrict__ Bp2,
                                              const float* __restrict__ asrc,
                                              const float* __restrict__ adst,
                                              ushort* __restrict__ hWb,
                                              float* __restrict__ esrc,
                                              float* __restrict__ edst) {
    __shared__ ushort hbf[2][16 * PADH];
    int t = threadIdx.x, w = t >> 6, l = t & 63;
    int m = l & 15, q = l >> 4;
    int n0w = blockIdx.x * 32 + w * 16;
    bool active = (n0w < NN);
    int nb = active ? n0w : 0;

    const float4* h4g = reinterpret_cast<const float4*>(hin) + (size_t)nb * 32;
    const float4* g4  = reinterpret_cast<const float4*>(g);
    const float4* be4 = reinterpret_cast<const float4*>(be);
    #pragma unroll
    for (int i = 0; i < 8; ++i) {
        int f4 = l + 64 * i;
        int node = f4 >> 5, c4 = f4 & 31;
        float4 v = h4g[f4];
        float s1 = v.x + v.y + v.z + v.w;
        float s2 = fmaf(v.x, v.x, fmaf(v.y, v.y, fmaf(v.z, v.z, v.w * v.w)));
        #pragma unroll
        for (int mk = 1; mk < 32; mk <<= 1) {
            s1 += __shfl_xor(s1, mk, 64);
            s2 += __shfl_xor(s2, mk, 64);
        }
        float mu = s1 * (1.f / 128.f);
        float var = s2 * (1.f / 128.f) - mu * mu;
        float rs = rsqrtf(var + 1e-5f);
        float4 gg = g4[c4], bb = be4[c4];
        ushort4 pk;
        pk.x = f2b(gelu_f((v.x - mu) * rs * gg.x + bb.x));
        pk.y = f2b(gelu_f((v.y - mu) * rs * gg.y + bb.y));
        pk.z = f2b(gelu_f((v.z - mu) * rs * gg.z + bb.z));
        pk.w = f2b(gelu_f((v.w - mu) * rs * gg.w + bb.w));
        *reinterpret_cast<ushort4*>(&hbf[w][node * PADH + c4 * 4]) = pk;
    }
    __syncthreads();

    const short8* B2 = reinterpret_cast<const short8*>(Bp2);
    floatx4 acc2[8];
    #pragma unroll
    for (int T = 0; T < 8; ++T) acc2[T] = (floatx4){0.f, 0.f, 0.f, 0.f};
    #pragma unroll
    for (int s = 0; s < 4; ++s) {
        short8 a = *reinterpret_cast<const short8*>(&hbf[w][m * PADH + s * 32 + q * 8]);
        #pragma unroll
        for (int T = 0; T < 8; ++T) {
            short8 b = B2[(T * 4 + s) * 64 + l];
            acc2[T] = __builtin_amdgcn_mfma_f32_16x16x32_bf16(a, b, acc2[T], 0, 0, 0);
        }
    }

    float as_[8], ad_[8];
    #pragma unroll
    for (int T = 0; T < 8; ++T) {
        int c = T * 16 + m;
        as_[T] = asrc[c]; ad_[T] = adst[c];
    }
    if (active) {
        #pragma unroll
        for (int j = 0; j < 4; ++j)
            #pragma unroll
            for (int T = 0; T < 8; ++T)
                hWb[(size_t)(n0w + q * 4 + j) * HID + T * 16 + m] = f2b(acc2[T][j]);
    }
    #pragma unroll
    for (int j = 0; j < 4; ++j) {
        #pragma unroll
        for (int h = 0; h < 4; ++h) {
            float v1 = fmaf(acc2[2 * h][j], as_[2 * h], acc2[2 * h + 1][j] * as_[2 * h + 1]);
            float v2 = fmaf(acc2[2 * h][j], ad_[2 * h], acc2[2 * h + 1][j] * ad_[2 * h + 1]);
            #pragma unroll
            for (int mk = 1; mk < 16; mk <<= 1) {
                v1 += __shfl_xor(v1, mk, 64);
                v2 += __shfl_xor(v2, mk, 64);
            }
            if (m == 0 && active) {
                esrc[(n0w + q * 4 + j) * 4 + h] = v1;
                edst[(n0w + q * 4 + j) * 4 + h] = v2;
            }
        }
    }
}

// ------- edge-parallel attention weights -------

__global__ __launch_bounds__(256) void k_edgew(const int* __restrict__ csr,
                                               const int* __restrict__ dstid,
                                               const float* __restrict__ esrc,
                                               const float* __restrict__ edst,
                                               ushort* __restrict__ wexp) {
    int i = blockIdx.x * 256 + threadIdx.x;
    if (i >= ETOT) return;
    int s = csr[i], d = dstid[i];
    float4 es = reinterpret_cast<const float4*>(esrc)[s];
    float4 ed = reinterpret_cast<const float4*>(edst)[d];
    float e0 = es.x + ed.x, e1 = es.y + ed.y, e2 = es.z + ed.z, e3 = es.w + ed.w;
    e0 = __expf(fmaxf(e0, 0.2f * e0));
    e1 = __expf(fmaxf(e1, 0.2f * e1));
    e2 = __expf(fmaxf(e2, 0.2f * e2));
    e3 = __expf(fmaxf(e3, 0.2f * e3));
    ushort4 pk = { f2b(e0), f2b(e1), f2b(e2), f2b(e3) };
    reinterpret_cast<ushort4*>(wexp)[i] = pk;
}

// ------- GAT aggregate v3: one wave per node, lane = column pair -------
// No barriers, no LDS, no reductions (per-lane dsum is per-head already).
// Per 8-edge chunk: 1 coalesced csr batch load (shfl-broadcast), 8 independent
// 4B row loads (256 B/wave each), 8 independent wexp loads; next csr batch
// prefetched. ~10 loads in flight per wave.

__global__ __launch_bounds__(256) void k_gat(const ushort* __restrict__ hWb,
                                             const ushort* __restrict__ wexp,
                                             const int* __restrict__ off,
                                             const int* __restrict__ csr,
                                             const float* __restrict__ bg,
                                             float* __restrict__ out) {
    int t = threadIdx.x;
    int wv = t >> 6, c = t & 63;       // lane c owns cols 2c, 2c+1
    int h  = c >> 4;                   // head of both cols
    int n  = blockIdx.x * 4 + wv;      // grid = NN/4 exactly
    int o0 = off[n], o1 = off[n + 1];
    const uint* hw2 = reinterpret_cast<const uint*>(hWb);

    float accx = 0.f, accy = 0.f, dsum = 0.f;
    int base = o0;
    int nIter = (o1 - o0 + 7) >> 3;
    // prologue: csr batch for chunk 0 (lanes 0-7 hold csr[base..base+7])
    int csrv = csr[min(base + (c & 7), ETOT - 1)];

    for (int it = 0; it < nIter; ++it) {
        int nxt = base + 8;
        int csrv_n = csr[min(nxt + (c & 7), ETOT - 1)];   // prefetch next batch
        uint  rows[8];
        float w[8];
        #pragma unroll
        for (int j = 0; j < 8; ++j) {
            int e = base + j;
            int src = __shfl(csrv, j, 64);
            bool valid = e < o1;
            src = valid ? src : 0;
            rows[j] = hw2[(size_t)src * 64 + c];
            ushort ub = wexp[(size_t)min(e, ETOT - 1) * 4 + h];
            w[j] = valid ? __uint_as_float(((unsigned)ub) << 16) : 0.f;
        }
        #pragma unroll
        for (int j = 0; j < 8; ++j) {
            accx = fmaf(w[j], __uint_as_float(rows[j] << 16),         accx);
            accy = fmaf(w[j], __uint_as_float(rows[j] & 0xffff0000u), accy);
            dsum += w[j];
        }
        base = nxt;
        csrv = csrv_n;
    }

    float inv = 1.0f / dsum;           // dsum identical across lanes of same head
    float2 bgv = reinterpret_cast<const float2*>(bg)[c];
    float2 res;
    res.x = accx * inv + bgv.x;
    res.y = accy * inv + bgv.y;
    reinterpret_cast<float2*>(out)[(size_t)n * 64 + c] = res;
}

// ---------------- output linear: fp32 register-tiled 4 nodes x 4 cols ----------------

__global__ __launch_bounds__(64) void k_out(const float* __restrict__ h,
                                            const float* __restrict__ w,
                                            const float* __restrict__ b,
                                            float* __restrict__ out) {
    __shared__ __align__(16) float hr[16 * 132];
    int t = threadIdx.x, n0 = blockIdx.x * 16;
    const float4* h4g = reinterpret_cast<const float4*>(h) + (size_t)n0 * 32;
    float4* hr4 = reinterpret_cast<float4*>(hr);
    #pragma unroll
    for (int i = 0; i < 8; ++i) {
        int f4 = t + 64 * i;
        hr4[(f4 >> 5) * 33 + (f4 & 31)] = h4g[f4];
    }
    __syncthreads();
    int cg = t & 15, ng = t >> 4;
    const float4* w4 = reinterpret_cast<const float4*>(w);
    float4 bb = reinterpret_cast<const float4*>(b)[cg];
    float4 acc[4] = {bb, bb, bb, bb};
    for (int k4 = 0; k4 < 32; ++k4) {
        float4 w0 = w4[(k4 * 4 + 0) * 16 + cg];
        float4 w1 = w4[(k4 * 4 + 1) * 16 + cg];
        float4 w2 = w4[(k4 * 4 + 2) * 16 + cg];
        float4 w3 = w4[(k4 * 4 + 3) * 16 + cg];
        #pragma unroll
        for (int r = 0; r < 4; ++r) {
            float4 hv = hr4[(ng * 4 + r) * 33 + k4];
            acc[r].x = fmaf(hv.x, w0.x, fmaf(hv.y, w1.x, fmaf(hv.z, w2.x, fmaf(hv.w, w3.x, acc[r].x))));
            acc[r].y = fmaf(hv.x, w0.y, fmaf(hv.y, w1.y, fmaf(hv.z, w2.y, fmaf(hv.w, w3.y, acc[r].y))));
            acc[r].z = fmaf(hv.x, w0.z, fmaf(hv.y, w1.z, fmaf(hv.z, w2.z, fmaf(hv.w, w3.z, acc[r].z))));
            acc[r].w = fmaf(hv.x, w0.w, fmaf(hv.y, w1.w, fmaf(hv.z, w2.w, fmaf(hv.w, w3.w, acc[r].w))));
        }
    }
    float4* o4 = reinterpret_cast<float4*>(out) + (size_t)n0 * 16;
    #pragma unroll
    for (int r = 0; r < 4; ++r) o4[(ng * 4 + r) * 16 + cg] = acc[r];
}

extern "C" void kernel_launch(void* const* d_in, const int* in_sizes, int n_in,
                              void* d_out, int out_size, void* d_ws, size_t ws_size,
                              hipStream_t stream) {
    const float* x    = (const float*)d_in[0];
    const int*   ei   = (const int*)  d_in[1];
    const float* w_in = (const float*)d_in[2];
    const float* b_in = (const float*)d_in[3];
    const float* g1   = (const float*)d_in[4];
    const float* be1  = (const float*)d_in[5];
    const float* W1   = (const float*)d_in[6];
    const float* as1  = (const float*)d_in[7];
    const float* ad1  = (const float*)d_in[8];
    const float* bg1  = (const float*)d_in[9];
    const float* g2   = (const float*)d_in[10];
    const float* be2  = (const float*)d_in[11];
    const float* W2   = (const float*)d_in[12];
    const float* as2  = (const float*)d_in[13];
    const float* ad2  = (const float*)d_in[14];
    const float* bg2  = (const float*)d_in[15];
    const float* w_o  = (const float*)d_in[16];
    const float* b_o  = (const float*)d_in[17];
    float* out = (float*)d_out;

    char* p = (char*)d_ws;
    auto take = [&](size_t bytes) {
        void* r = p;
        p += (bytes + 255) & ~(size_t)255;
        return r;
    };
    float*  gout  = (float*)take((size_t)NN * HID * 4);
    float*  h2    = (float*)take((size_t)NN * HID * 4);
    ushort* hWb   = (ushort*)take((size_t)NN * HID * 2);
    float*  esrc  = (float*)take((size_t)NN * 4 * 4);
    float*  edst  = (float*)take((size_t)NN * 4 * 4);
    int*    off   = (int*)take((size_t)(NN + 1) * 4);
    int*    csr   = (int*)take((size_t)ETOT * 4);
    int*    dstid = (int*)take((size_t)ETOT * 4);
    size_t ovl = (size_t)ETOT * 8;
    size_t tsz = (size_t)NBK * CAP * 4;
    ushort* wexp  = (ushort*)take(ovl > tsz ? ovl : tsz);
    int*    tmp   = (int*)wexp;
    int*    bcur  = (int*)take((size_t)NBK * 4);
    int*    bstart= (int*)take((size_t)NBK * 4);
    ushort* Bp1   = (ushort*)take((size_t)1024 * 16);
    ushort* BpW1  = (ushort*)take((size_t)2048 * 16);
    ushort* BpW2  = (ushort*)take((size_t)2048 * 16);

    k_pack<<<4, 256, 0, stream>>>(w_in, Bp1, 64, 128);
    k_pack<<<8, 256, 0, stream>>>(W1, BpW1, 128, 128);
    k_pack<<<8, 256, 0, stream>>>(W2, BpW2, 128, 128);

    k_zero      <<<(NBK + 255) / 256, 256, 0, stream>>>(bcur);
    k_bucket    <<<BBLK, 1024, 0, stream>>>(ei, bcur, tmp);
    k_bscan     <<<1, NBK, 0, stream>>>(bcur, bstart, off);
    k_bucket2csr<<<NBK, 256, 0, stream>>>(tmp, bcur, bstart, off, csr, dstid);

    int gfeat = (NN + 31) / 32;
    k_infeat<<<gfeat, 128, 0, stream>>>(x, Bp1, b_in, g1, be1, BpW1, as1, ad1, hWb, esrc, edst);
    k_edgew <<<(ETOT + 255) / 256, 256, 0, stream>>>(csr, dstid, esrc, edst, wexp);
    k_gat   <<<NN / 4, 256, 0, stream>>>(hWb, wexp, off, csr, bg1, gout);
    k_feat  <<<gfeat, 128, 0, stream>>>(gout, g2, be2, BpW2, as2, ad2, hWb, esrc, edst);
    k_edgew <<<(ETOT + 255) / 256, 256, 0, stream>>>(csr, dstid, esrc, edst, wexp);
    k_gat   <<<NN / 4, 256, 0, stream>>>(hWb, wexp, off, csr, bg2, h2);
    k_out   <<<NN / 16, 64, 0, stream>>>(h2, w_o, b_o, out);
}

// Round 8
// 345.095 us; speedup vs baseline: 1.2850x; 1.2850x over previous
//
#include <hip/hip_runtime.h>
#include <hip/hip_bf16.h>
#include <math.h>

#define NN   50000
#define EE   1600000
#define ETOT (EE + NN)
#define HID  128
#define INF_ 64
#define OUTF 64

// bucketed CSR build
#define NBK  1024   // buckets (contiguous dst ranges)
#define NPB  49     // nodes per bucket (1024*49 = 50176 >= NN)
#define CAP  3072   // per-bucket capacity; mean ~1617, 1.9x headroom
#define BBLK 256    // blocks for k_bucket
#define CHUNK ((ETOT + BBLK - 1) / BBLK)   // 6446 edges per block

#define PADX 72     // xbf row stride (ushorts), 144 B (16B-aligned)
#define PADH 136    // hbf row stride (ushorts), 272 B (16B-aligned)

typedef short  short8  __attribute__((ext_vector_type(8)));
typedef float  floatx4 __attribute__((ext_vector_type(4)));

__device__ __forceinline__ ushort f2b(float f) {
    __hip_bfloat16 h = __float2bfloat16(f);
    return *reinterpret_cast<ushort*>(&h);
}

// fast tanh-gelu: gelu(x) = x * t/(t+1), t = exp(2u), u = 0.79788456*(x+0.044715x^3)
__device__ __forceinline__ float gelu_f(float x) {
    float x2 = x * x;
    float u  = 0.7978845608f * fmaf(0.044715f * x2, x, x);
    u = fminf(u, 40.f);                 // overflow guard (LN'd inputs never get here)
    float t = __expf(2.f * u);
    return x * t / (t + 1.f);
}

// ---------------- CSR build (bucketed counting sort) ----------------

__global__ void k_zero(int* bcur) {
    int i = blockIdx.x * 256 + threadIdx.x;
    if (i < NBK) bcur[i] = 0;
}

__global__ __launch_bounds__(1024) void k_bucket(const int* __restrict__ ei,
                                                 int* bcur, int* __restrict__ tmp) {
    __shared__ unsigned sortedv[CHUNK];
    __shared__ int hist[NBK], gbase[NBK], loff[NBK], lcur[NBK];
    int t = threadIdx.x;
    int lo = blockIdx.x * CHUNK;
    int hi = min(lo + CHUNK, ETOT);
    int bsize = hi - lo;
    hist[t] = 0;
    __syncthreads();
    for (int i = lo + t; i < hi; i += 1024) {
        int d = (i < EE) ? ei[EE + i] : i - EE;
        atomicAdd(&hist[d / NPB], 1);
    }
    __syncthreads();
    {
        int c = hist[t];
        gbase[t] = (c > 0) ? atomicAdd(&bcur[t], c) : 0;
        loff[t] = c;
    }
    __syncthreads();
    for (int d = 1; d < NBK; d <<= 1) {
        int v = (t >= d) ? loff[t - d] : 0;
        __syncthreads();
        loff[t] += v;
        __syncthreads();
    }
    {
        int ex = loff[t] - hist[t];
        __syncthreads();
        loff[t] = ex;
        lcur[t] = ex;
    }
    __syncthreads();
    for (int i = lo + t; i < hi; i += 1024) {
        unsigned s, d;
        if (i < EE) { s = (unsigned)ei[i]; d = (unsigned)ei[EE + i]; }
        else        { s = d = (unsigned)(i - EE); }
        unsigned b = d / NPB;
        int p = atomicAdd(&lcur[b], 1);
        sortedv[p] = (b << 22) | (s << 6) | (d - b * NPB);
    }
    __syncthreads();
    for (int i = t; i < bsize; i += 1024) {
        unsigned v = sortedv[i];
        unsigned b = v >> 22;
        int pp = gbase[b] + i - loff[b];
        if (pp < CAP) tmp[b * CAP + pp] = (int)(v & 0x3FFFFFu);
    }
}

__global__ __launch_bounds__(1024) void k_bscan(const int* __restrict__ bcur,
                                                int* __restrict__ bstart,
                                                int* __restrict__ off) {
    __shared__ int s[NBK];
    int t = threadIdx.x;
    int v0 = bcur[t];
    s[t] = v0;
    __syncthreads();
    for (int d = 1; d < NBK; d <<= 1) {
        int v = (t >= d) ? s[t - d] : 0;
        __syncthreads();
        s[t] += v;
        __syncthreads();
    }
    bstart[t] = s[t] - v0;
    if (t == 0) off[NN] = ETOT;
}

__global__ __launch_bounds__(256) void k_bucket2csr(const int* __restrict__ tmp,
                                                    const int* __restrict__ bcur,
                                                    const int* __restrict__ bstart,
                                                    int* __restrict__ off,
                                                    int* __restrict__ csr,
                                                    int* __restrict__ dstid) {
    __shared__ int sE[CAP];
    __shared__ int lcnt[NPB];
    __shared__ int loff[NPB];
    int b = blockIdx.x, t = threadIdx.x;
    int n0    = b * NPB;
    int bsize = min(bcur[b], CAP);
    int base  = bstart[b];
    if (t < NPB) lcnt[t] = 0;
    for (int i = t; i < bsize; i += 256) sE[i] = tmp[b * CAP + i];
    __syncthreads();
    for (int i = t; i < bsize; i += 256) atomicAdd(&lcnt[sE[i] & 63], 1);
    __syncthreads();
    if (t == 0) {
        int run = 0;
        for (int j = 0; j < NPB; ++j) { loff[j] = run; run += lcnt[j]; }
    }
    __syncthreads();
    if (t < NPB) {
        if (n0 + t < NN) off[n0 + t] = base + loff[t];
        lcnt[t] = loff[t];
    }
    __syncthreads();
    for (int i = t; i < bsize; i += 256) {
        int v   = sE[i];
        int d   = v & 63;
        int pos = base + atomicAdd(&lcnt[d], 1);
        csr[pos]   = v >> 6;
        dstid[pos] = n0 + d;
    }
}

// ---------------- weight packing into MFMA B-fragment order ----------------

__global__ void k_pack(const float* __restrict__ W, ushort* __restrict__ dst,
                       int K, int N) {
    int tid = blockIdx.x * 256 + threadIdx.x;
    int kst = K >> 5;
    int total = (N >> 4) * kst * 64;
    if (tid >= total) return;
    int l = tid & 63;
    int s = (tid >> 6) % kst;
    int T = tid / (kst * 64);
    int m = l & 15, q = l >> 4;
    ushort o[8];
    #pragma unroll
    for (int j = 0; j < 8; ++j)
        o[j] = f2b(W[(s * 32 + q * 8 + j) * N + T * 16 + m]);
    uint4 pk;
    pk.x = (unsigned)o[0] | ((unsigned)o[1] << 16);
    pk.y = (unsigned)o[2] | ((unsigned)o[3] << 16);
    pk.z = (unsigned)o[4] | ((unsigned)o[5] << 16);
    pk.w = (unsigned)o[6] | ((unsigned)o[7] << 16);
    reinterpret_cast<uint4*>(dst)[tid] = pk;
}

// ------- MFMA fused: x@w_in -> +bias -> LN -> GELU -> @W -> hWb + scores -------

__global__ __launch_bounds__(128) void k_infeat(const float* __restrict__ x,
                                                const ushort* __restrict__ Bp1,
                                                const float* __restrict__ bin,
                                                const float* __restrict__ g,
                                                const float* __restrict__ be,
                                                const ushort* __restrict__ Bp2,
                                                const float* __restrict__ asrc,
                                                const float* __restrict__ adst,
                                                ushort* __restrict__ hWb,
                                                float* __restrict__ esrc,
                                                float* __restrict__ edst) {
    __shared__ ushort xbf[2][16 * PADX];
    __shared__ ushort hbf[2][16 * PADH];
    int t = threadIdx.x, w = t >> 6, l = t & 63;
    int m = l & 15, q = l >> 4;
    int n0w = blockIdx.x * 32 + w * 16;
    bool active = (n0w < NN);
    int nb = active ? n0w : 0;

    const float4* x4 = reinterpret_cast<const float4*>(x) + (size_t)nb * 16;
    #pragma unroll
    for (int i = 0; i < 4; ++i) {
        int f4 = l + 64 * i;
        int node = f4 >> 4, c4 = f4 & 15;
        float4 v = x4[f4];
        ushort4 pk = { f2b(v.x), f2b(v.y), f2b(v.z), f2b(v.w) };
        *reinterpret_cast<ushort4*>(&xbf[w][node * PADX + c4 * 4]) = pk;
    }
    __syncthreads();

    const short8* B1 = reinterpret_cast<const short8*>(Bp1);
    floatx4 acc1[8];
    #pragma unroll
    for (int T = 0; T < 8; ++T) acc1[T] = (floatx4){0.f, 0.f, 0.f, 0.f};
    #pragma unroll
    for (int s = 0; s < 2; ++s) {
        short8 a = *reinterpret_cast<const short8*>(&xbf[w][m * PADX + s * 32 + q * 8]);
        #pragma unroll
        for (int T = 0; T < 8; ++T) {
            short8 b = B1[(T * 2 + s) * 64 + l];
            acc1[T] = __builtin_amdgcn_mfma_f32_16x16x32_bf16(a, b, acc1[T], 0, 0, 0);
        }
    }

    float bc[8], gc[8], bec[8];
    #pragma unroll
    for (int T = 0; T < 8; ++T) {
        int c = T * 16 + m;
        bc[T] = bin[c]; gc[T] = g[c]; bec[T] = be[c];
    }
    #pragma unroll
    for (int j = 0; j < 4; ++j) {
        float s1 = 0.f, s2 = 0.f;
        #pragma unroll
        for (int T = 0; T < 8; ++T) {
            float v = acc1[T][j] + bc[T];
            s1 += v; s2 = fmaf(v, v, s2);
        }
        #pragma unroll
        for (int mk = 1; mk < 16; mk <<= 1) {
            s1 += __shfl_xor(s1, mk, 64);
            s2 += __shfl_xor(s2, mk, 64);
        }
        float mu = s1 * (1.f / 128.f);
        float var = s2 * (1.f / 128.f) - mu * mu;
        float rs = rsqrtf(var + 1e-5f);
        #pragma unroll
        for (int T = 0; T < 8; ++T) {
            float v = acc1[T][j] + bc[T];
            float y = (v - mu) * rs * gc[T] + bec[T];
            hbf[w][(q * 4 + j) * PADH + T * 16 + m] = f2b(gelu_f(y));
        }
    }
    __syncthreads();

    const short8* B2 = reinterpret_cast<const short8*>(Bp2);
    floatx4 acc2[8];
    #pragma unroll
    for (int T = 0; T < 8; ++T) acc2[T] = (floatx4){0.f, 0.f, 0.f, 0.f};
    #pragma unroll
    for (int s = 0; s < 4; ++s) {
        short8 a = *reinterpret_cast<const short8*>(&hbf[w][m * PADH + s * 32 + q * 8]);
        #pragma unroll
        for (int T = 0; T < 8; ++T) {
            short8 b = B2[(T * 4 + s) * 64 + l];
            acc2[T] = __builtin_amdgcn_mfma_f32_16x16x32_bf16(a, b, acc2[T], 0, 0, 0);
        }
    }

    float as_[8], ad_[8];
    #pragma unroll
    for (int T = 0; T < 8; ++T) {
        int c = T * 16 + m;
        as_[T] = asrc[c]; ad_[T] = adst[c];
    }
    if (active) {
        #pragma unroll
        for (int j = 0; j < 4; ++j)
            #pragma unroll
            for (int T = 0; T < 8; ++T)
                hWb[(size_t)(n0w + q * 4 + j) * HID + T * 16 + m] = f2b(acc2[T][j]);
    }
    #pragma unroll
    for (int j = 0; j < 4; ++j) {
        #pragma unroll
        for (int h = 0; h < 4; ++h) {
            float v1 = fmaf(acc2[2 * h][j], as_[2 * h], acc2[2 * h + 1][j] * as_[2 * h + 1]);
            float v2 = fmaf(acc2[2 * h][j], ad_[2 * h], acc2[2 * h + 1][j] * ad_[2 * h + 1]);
            #pragma unroll
            for (int mk = 1; mk < 16; mk <<= 1) {
                v1 += __shfl_xor(v1, mk, 64);
                v2 += __shfl_xor(v2, mk, 64);
            }
            if (m == 0 && active) {
                esrc[(n0w + q * 4 + j) * 4 + h] = v1;
                edst[(n0w + q * 4 + j) * 4 + h] = v2;
            }
        }
    }
}

// ------- MFMA fused layer-2: LN(gout) -> GELU -> @W2 -> hWb + scores -------

__global__ __launch_bounds__(128) void k_feat(const float* __restrict__ hin,
                                              const float* __restrict__ g,
                                              const float* __restrict__ be,
                                              const ushort* __restrict__ Bp2,
                                              const float* __restrict__ asrc,
                                              const float* __restrict__ adst,
                                              ushort* __restrict__ hWb,
                                              float* __restrict__ esrc,
                                              float* __restrict__ edst) {
    __shared__ ushort hbf[2][16 * PADH];
    int t = threadIdx.x, w = t >> 6, l = t & 63;
    int m = l & 15, q = l >> 4;
    int n0w = blockIdx.x * 32 + w * 16;
    bool active = (n0w < NN);
    int nb = active ? n0w : 0;

    const float4* h4g = reinterpret_cast<const float4*>(hin) + (size_t)nb * 32;
    const float4* g4  = reinterpret_cast<const float4*>(g);
    const float4* be4 = reinterpret_cast<const float4*>(be);
    #pragma unroll
    for (int i = 0; i < 8; ++i) {
        int f4 = l + 64 * i;
        int node = f4 >> 5, c4 = f4 & 31;
        float4 v = h4g[f4];
        float s1 = v.x + v.y + v.z + v.w;
        float s2 = fmaf(v.x, v.x, fmaf(v.y, v.y, fmaf(v.z, v.z, v.w * v.w)));
        #pragma unroll
        for (int mk = 1; mk < 32; mk <<= 1) {
            s1 += __shfl_xor(s1, mk, 64);
            s2 += __shfl_xor(s2, mk, 64);
        }
        float mu = s1 * (1.f / 128.f);
        float var = s2 * (1.f / 128.f) - mu * mu;
        float rs = rsqrtf(var + 1e-5f);
        float4 gg = g4[c4], bb = be4[c4];
        ushort4 pk;
        pk.x = f2b(gelu_f((v.x - mu) * rs * gg.x + bb.x));
        pk.y = f2b(gelu_f((v.y - mu) * rs * gg.y + bb.y));
        pk.z = f2b(gelu_f((v.z - mu) * rs * gg.z + bb.z));
        pk.w = f2b(gelu_f((v.w - mu) * rs * gg.w + bb.w));
        *reinterpret_cast<ushort4*>(&hbf[w][node * PADH + c4 * 4]) = pk;
    }
    __syncthreads();

    const short8* B2 = reinterpret_cast<const short8*>(Bp2);
    floatx4 acc2[8];
    #pragma unroll
    for (int T = 0; T < 8; ++T) acc2[T] = (floatx4){0.f, 0.f, 0.f, 0.f};
    #pragma unroll
    for (int s = 0; s < 4; ++s) {
        short8 a = *reinterpret_cast<const short8*>(&hbf[w][m * PADH + s * 32 + q * 8]);
        #pragma unroll
        for (int T = 0; T < 8; ++T) {
            short8 b = B2[(T * 4 + s) * 64 + l];
            acc2[T] = __builtin_amdgcn_mfma_f32_16x16x32_bf16(a, b, acc2[T], 0, 0, 0);
        }
    }

    float as_[8], ad_[8];
    #pragma unroll
    for (int T = 0; T < 8; ++T) {
        int c = T * 16 + m;
        as_[T] = asrc[c]; ad_[T] = adst[c];
    }
    if (active) {
        #pragma unroll
        for (int j = 0; j < 4; ++j)
            #pragma unroll
            for (int T = 0; T < 8; ++T)
                hWb[(size_t)(n0w + q * 4 + j) * HID + T * 16 + m] = f2b(acc2[T][j]);
    }
    #pragma unroll
    for (int j = 0; j < 4; ++j) {
        #pragma unroll
        for (int h = 0; h < 4; ++h) {
            float v1 = fmaf(acc2[2 * h][j], as_[2 * h], acc2[2 * h + 1][j] * as_[2 * h + 1]);
            float v2 = fmaf(acc2[2 * h][j], ad_[2 * h], acc2[2 * h + 1][j] * ad_[2 * h + 1]);
            #pragma unroll
            for (int mk = 1; mk < 16; mk <<= 1) {
                v1 += __shfl_xor(v1, mk, 64);
                v2 += __shfl_xor(v2, mk, 64);
            }
            if (m == 0 && active) {
                esrc[(n0w + q * 4 + j) * 4 + h] = v1;
                edst[(n0w + q * 4 + j) * 4 + h] = v2;
            }
        }
    }
}

// ------- edge-parallel attention weights -------

__global__ __launch_bounds__(256) void k_edgew(const int* __restrict__ csr,
                                               const int* __restrict__ dstid,
                                               const float* __restrict__ esrc,
                                               const float* __restrict__ edst,
                                               ushort* __restrict__ wexp) {
    int i = blockIdx.x * 256 + threadIdx.x;
    if (i >= ETOT) return;
    int s = csr[i], d = dstid[i];
    float4 es = reinterpret_cast<const float4*>(esrc)[s];
    float4 ed = reinterpret_cast<const float4*>(edst)[d];
    float e0 = es.x + ed.x, e1 = es.y + ed.y, e2 = es.z + ed.z, e3 = es.w + ed.w;
    e0 = __expf(fmaxf(e0, 0.2f * e0));
    e1 = __expf(fmaxf(e1, 0.2f * e1));
    e2 = __expf(fmaxf(e2, 0.2f * e2));
    e3 = __expf(fmaxf(e3, 0.2f * e3));
    ushort4 pk = { f2b(e0), f2b(e1), f2b(e2), f2b(e3) };
    reinterpret_cast<ushort4*>(wexp)[i] = pk;
}

// ------- GAT aggregate v5: R6 layout + explicit 2-wide unrolled pipeline -------
// 128 thr = 2 waves x 4 edge-slots x 16 lane-groups (uint4 = 8 cols per lane).
// Each loop body: issue rows for batches it+2,it+3 and indices for it+4,it+5,
// THEN process batches it,it+1 -> >=2 row loads + 2 idx loads outstanding,
// structurally live (compiler can't collapse to load->use).

__global__ __launch_bounds__(128) void k_gat(const ushort* __restrict__ hWb,
                                             const ushort* __restrict__ wexp,
                                             const int* __restrict__ off,
                                             const int* __restrict__ csr,
                                             const float* __restrict__ bg,
                                             float* __restrict__ out) {
    __shared__ float redA[16][8];
    __shared__ float redD[16];
    int n = blockIdx.x, t = threadIdx.x;
    int wv = t >> 6, l = t & 63;
    int slot = l >> 4;          // lane bits 4-5 = edge slot
    int q    = l & 15;          // col group: cols 8q..8q+7
    int hq   = q >> 2;          // head of those cols
    int o0 = off[n], o1 = off[n + 1];
    const uint4* hw4 = reinterpret_cast<const uint4*>(hWb);
    float acc[8] = {0.f, 0.f, 0.f, 0.f, 0.f, 0.f, 0.f, 0.f};
    float dsum = 0.f;
    int nIter = (o1 - o0 + 15) >> 4;       // 16 edges per body (8 per wave)
    int e = o0 + wv * 4 + slot;            // this lane's batch-0 edge

    // prologue: indices for batches 0..3, rows for 0..1
    int eA = min(e,      ETOT - 1);
    int eB = min(e + 8,  ETOT - 1);
    int eC = min(e + 16, ETOT - 1);
    int eD = min(e + 24, ETOT - 1);
    int    srcA = csr[eA]; ushort ubA = wexp[eA * 4 + hq];
    int    srcB = csr[eB]; ushort ubB = wexp[eB * 4 + hq];
    int    srcC = csr[eC]; ushort ubC = wexp[eC * 4 + hq];
    int    srcD = csr[eD]; ushort ubD = wexp[eD * 4 + hq];
    uint4  rA = hw4[(size_t)srcA * 16 + q];
    uint4  rB = hw4[(size_t)srcB * 16 + q];

    for (int it = 0; it < nIter; ++it) {
        // issue rows it+2, it+3 (indices loaded 2 bodies ago — no wait chain)
        uint4 rC = hw4[(size_t)srcC * 16 + q];
        uint4 rD = hw4[(size_t)srcD * 16 + q];
        // prefetch indices it+4, it+5
        int eE = min(e + 32, ETOT - 1);
        int eF = min(e + 40, ETOT - 1);
        int    srcE = csr[eE]; ushort ubE = wexp[eE * 4 + hq];
        int    srcF = csr[eF]; ushort ubF = wexp[eF * 4 + hq];
        // process batch it (rA) and it+1 (rB)
        float wa = (e     < o1) ? __uint_as_float(((unsigned)ubA) << 16) : 0.f;
        float wb = (e + 8 < o1) ? __uint_as_float(((unsigned)ubB) << 16) : 0.f;
        acc[0] = fmaf(wa, __uint_as_float(rA.x << 16),          acc[0]);
        acc[1] = fmaf(wa, __uint_as_float(rA.x & 0xffff0000u),  acc[1]);
        acc[2] = fmaf(wa, __uint_as_float(rA.y << 16),          acc[2]);
        acc[3] = fmaf(wa, __uint_as_float(rA.y & 0xffff0000u),  acc[3]);
        acc[4] = fmaf(wa, __uint_as_float(rA.z << 16),          acc[4]);
        acc[5] = fmaf(wa, __uint_as_float(rA.z & 0xffff0000u),  acc[5]);
        acc[6] = fmaf(wa, __uint_as_float(rA.w << 16),          acc[6]);
        acc[7] = fmaf(wa, __uint_as_float(rA.w & 0xffff0000u),  acc[7]);
        acc[0] = fmaf(wb, __uint_as_float(rB.x << 16),          acc[0]);
        acc[1] = fmaf(wb, __uint_as_float(rB.x & 0xffff0000u),  acc[1]);
        acc[2] = fmaf(wb, __uint_as_float(rB.y << 16),          acc[2]);
        acc[3] = fmaf(wb, __uint_as_float(rB.y & 0xffff0000u),  acc[3]);
        acc[4] = fmaf(wb, __uint_as_float(rB.z << 16),          acc[4]);
        acc[5] = fmaf(wb, __uint_as_float(rB.z & 0xffff0000u),  acc[5]);
        acc[6] = fmaf(wb, __uint_as_float(rB.w << 16),          acc[6]);
        acc[7] = fmaf(wb, __uint_as_float(rB.w & 0xffff0000u),  acc[7]);
        dsum += wa + wb;
        e += 16;
        rA = rC; rB = rD;
        srcC = srcE; srcD = srcF;
        ubA = ubC; ubB = ubD; ubC = ubE; ubD = ubF;
    }
    // reduce across the 4 edge slots (lane bits 4 and 5)
    #pragma unroll
    for (int mk = 16; mk <= 32; mk <<= 1) {
        #pragma unroll
        for (int j = 0; j < 8; ++j) acc[j] += __shfl_xor(acc[j], mk, 64);
        dsum += __shfl_xor(dsum, mk, 64);
    }
    if (wv == 1 && l < 16) {
        #pragma unroll
        for (int j = 0; j < 8; ++j) redA[l][j] = acc[j];
        redD[l] = dsum;
    }
    __syncthreads();
    if (wv == 0 && l < 16) {
        float inv = 1.0f / (dsum + redD[l]);
        float4 r0, r1;
        r0.x = (acc[0] + redA[l][0]) * inv + bg[l * 8 + 0];
        r0.y = (acc[1] + redA[l][1]) * inv + bg[l * 8 + 1];
        r0.z = (acc[2] + redA[l][2]) * inv + bg[l * 8 + 2];
        r0.w = (acc[3] + redA[l][3]) * inv + bg[l * 8 + 3];
        r1.x = (acc[4] + redA[l][4]) * inv + bg[l * 8 + 4];
        r1.y = (acc[5] + redA[l][5]) * inv + bg[l * 8 + 5];
        r1.z = (acc[6] + redA[l][6]) * inv + bg[l * 8 + 6];
        r1.w = (acc[7] + redA[l][7]) * inv + bg[l * 8 + 7];
        float4* op = reinterpret_cast<float4*>(out + (size_t)n * HID + l * 8);
        op[0] = r0; op[1] = r1;
    }
}

// ---------------- output linear: fp32 register-tiled 4 nodes x 4 cols ----------------

__global__ __launch_bounds__(64) void k_out(const float* __restrict__ h,
                                            const float* __restrict__ w,
                                            const float* __restrict__ b,
                                            float* __restrict__ out) {
    __shared__ __align__(16) float hr[16 * 132];
    int t = threadIdx.x, n0 = blockIdx.x * 16;
    const float4* h4g = reinterpret_cast<const float4*>(h) + (size_t)n0 * 32;
    float4* hr4 = reinterpret_cast<float4*>(hr);
    #pragma unroll
    for (int i = 0; i < 8; ++i) {
        int f4 = t + 64 * i;
        hr4[(f4 >> 5) * 33 + (f4 & 31)] = h4g[f4];
    }
    __syncthreads();
    int cg = t & 15, ng = t >> 4;
    const float4* w4 = reinterpret_cast<const float4*>(w);
    float4 bb = reinterpret_cast<const float4*>(b)[cg];
    float4 acc[4] = {bb, bb, bb, bb};
    for (int k4 = 0; k4 < 32; ++k4) {
        float4 w0 = w4[(k4 * 4 + 0) * 16 + cg];
        float4 w1 = w4[(k4 * 4 + 1) * 16 + cg];
        float4 w2 = w4[(k4 * 4 + 2) * 16 + cg];
        float4 w3 = w4[(k4 * 4 + 3) * 16 + cg];
        #pragma unroll
        for (int r = 0; r < 4; ++r) {
            float4 hv = hr4[(ng * 4 + r) * 33 + k4];
            acc[r].x = fmaf(hv.x, w0.x, fmaf(hv.y, w1.x, fmaf(hv.z, w2.x, fmaf(hv.w, w3.x, acc[r].x))));
            acc[r].y = fmaf(hv.x, w0.y, fmaf(hv.y, w1.y, fmaf(hv.z, w2.y, fmaf(hv.w, w3.y, acc[r].y))));
            acc[r].z = fmaf(hv.x, w0.z, fmaf(hv.y, w1.z, fmaf(hv.z, w2.z, fmaf(hv.w, w3.z, acc[r].z))));
            acc[r].w = fmaf(hv.x, w0.w, fmaf(hv.y, w1.w, fmaf(hv.z, w2.w, fmaf(hv.w, w3.w, acc[r].w))));
        }
    }
    float4* o4 = reinterpret_cast<float4*>(out) + (size_t)n0 * 16;
    #pragma unroll
    for (int r = 0; r < 4; ++r) o4[(ng * 4 + r) * 16 + cg] = acc[r];
}

extern "C" void kernel_launch(void* const* d_in, const int* in_sizes, int n_in,
                              void* d_out, int out_size, void* d_ws, size_t ws_size,
                              hipStream_t stream) {
    const float* x    = (const float*)d_in[0];
    const int*   ei   = (const int*)  d_in[1];
    const float* w_in = (const float*)d_in[2];
    const float* b_in = (const float*)d_in[3];
    const float* g1   = (const float*)d_in[4];
    const float* be1  = (const float*)d_in[5];
    const float* W1   = (const float*)d_in[6];
    const float* as1  = (const float*)d_in[7];
    const float* ad1  = (const float*)d_in[8];
    const float* bg1  = (const float*)d_in[9];
    const float* g2   = (const float*)d_in[10];
    const float* be2  = (const float*)d_in[11];
    const float* W2   = (const float*)d_in[12];
    const float* as2  = (const float*)d_in[13];
    const float* ad2  = (const float*)d_in[14];
    const float* bg2  = (const float*)d_in[15];
    const float* w_o  = (const float*)d_in[16];
    const float* b_o  = (const float*)d_in[17];
    float* out = (float*)d_out;

    char* p = (char*)d_ws;
    auto take = [&](size_t bytes) {
        void* r = p;
        p += (bytes + 255) & ~(size_t)255;
        return r;
    };
    float*  gout  = (float*)take((size_t)NN * HID * 4);
    float*  h2    = (float*)take((size_t)NN * HID * 4);
    ushort* hWb   = (ushort*)take((size_t)NN * HID * 2);
    float*  esrc  = (float*)take((size_t)NN * 4 * 4);
    float*  edst  = (float*)take((size_t)NN * 4 * 4);
    int*    off   = (int*)take((size_t)(NN + 1) * 4);
    int*    csr   = (int*)take((size_t)ETOT * 4);
    int*    dstid = (int*)take((size_t)ETOT * 4);
    size_t ovl = (size_t)ETOT * 8;
    size_t tsz = (size_t)NBK * CAP * 4;
    ushort* wexp  = (ushort*)take(ovl > tsz ? ovl : tsz);
    int*    tmp   = (int*)wexp;
    int*    bcur  = (int*)take((size_t)NBK * 4);
    int*    bstart= (int*)take((size_t)NBK * 4);
    ushort* Bp1   = (ushort*)take((size_t)1024 * 16);
    ushort* BpW1  = (ushort*)take((size_t)2048 * 16);
    ushort* BpW2  = (ushort*)take((size_t)2048 * 16);

    k_pack<<<4, 256, 0, stream>>>(w_in, Bp1, 64, 128);
    k_pack<<<8, 256, 0, stream>>>(W1, BpW1, 128, 128);
    k_pack<<<8, 256, 0, stream>>>(W2, BpW2, 128, 128);

    k_zero      <<<(NBK + 255) / 256, 256, 0, stream>>>(bcur);
    k_bucket    <<<BBLK, 1024, 0, stream>>>(ei, bcur, tmp);
    k_bscan     <<<1, NBK, 0, stream>>>(bcur, bstart, off);
    k_bucket2csr<<<NBK, 256, 0, stream>>>(tmp, bcur, bstart, off, csr, dstid);

    int gfeat = (NN + 31) / 32;
    k_infeat<<<gfeat, 128, 0, stream>>>(x, Bp1, b_in, g1, be1, BpW1, as1, ad1, hWb, esrc, edst);
    k_edgew <<<(ETOT + 255) / 256, 256, 0, stream>>>(csr, dstid, esrc, edst, wexp);
    k_gat   <<<NN, 128, 0, stream>>>(hWb, wexp, off, csr, bg1, gout);
    k_feat  <<<gfeat, 128, 0, stream>>>(gout, g2, be2, BpW2, as2, ad2, hWb, esrc, edst);
    k_edgew <<<(ETOT + 255) / 256, 256, 0, stream>>>(csr, dstid, esrc, edst, wexp);
    k_gat   <<<NN, 128, 0, stream>>>(hWb, wexp, off, csr, bg2, h2);
    k_out   <<<NN / 16, 64, 0, stream>>>(h2, w_o, b_o, out);
}

// Round 9
// 323.920 us; speedup vs baseline: 1.3690x; 1.0654x over previous
//
#include <hip/hip_runtime.h>
#include <hip/hip_bf16.h>
#include <math.h>

#define NN   50000
#define EE   1600000
#define ETOT (EE + NN)
#define HID  128
#define INF_ 64
#define OUTF 64

// bucketed CSR build
#define NBK  1024   // buckets (contiguous dst ranges)
#define NPB  49     // nodes per bucket (1024*49 = 50176 >= NN)
#define CAP  3072   // per-bucket capacity; mean ~1617, 1.9x headroom
#define BBLK 256    // blocks for k_bucket
#define CHUNK ((ETOT + BBLK - 1) / BBLK)   // 6446 edges per block

#define PADX 72     // xbf row stride (ushorts), 144 B (16B-aligned)
#define PADH 136    // hbf row stride (ushorts), 272 B (16B-aligned)

typedef short  short8  __attribute__((ext_vector_type(8)));
typedef float  floatx4 __attribute__((ext_vector_type(4)));

__device__ __forceinline__ ushort f2b(float f) {
    __hip_bfloat16 h = __float2bfloat16(f);
    return *reinterpret_cast<ushort*>(&h);
}

// fast tanh-gelu: gelu(x) = x * t/(t+1), t = exp(2u), u = 0.79788456*(x+0.044715x^3)
__device__ __forceinline__ float gelu_f(float x) {
    float x2 = x * x;
    float u  = 0.7978845608f * fmaf(0.044715f * x2, x, x);
    u = fminf(u, 40.f);                 // overflow guard (LN'd inputs never get here)
    float t = __expf(2.f * u);
    return x * t / (t + 1.f);
}

// ---------------- CSR build (bucketed counting sort) ----------------

__global__ void k_zero(int* bcur) {
    int i = blockIdx.x * 256 + threadIdx.x;
    if (i < NBK) bcur[i] = 0;
}

__global__ __launch_bounds__(1024) void k_bucket(const int* __restrict__ ei,
                                                 int* bcur, int* __restrict__ tmp) {
    __shared__ unsigned sortedv[CHUNK];
    __shared__ int hist[NBK], gbase[NBK], loff[NBK], lcur[NBK];
    int t = threadIdx.x;
    int lo = blockIdx.x * CHUNK;
    int hi = min(lo + CHUNK, ETOT);
    int bsize = hi - lo;
    hist[t] = 0;
    __syncthreads();
    for (int i = lo + t; i < hi; i += 1024) {
        int d = (i < EE) ? ei[EE + i] : i - EE;
        atomicAdd(&hist[d / NPB], 1);
    }
    __syncthreads();
    {
        int c = hist[t];
        gbase[t] = (c > 0) ? atomicAdd(&bcur[t], c) : 0;
        loff[t] = c;
    }
    __syncthreads();
    for (int d = 1; d < NBK; d <<= 1) {
        int v = (t >= d) ? loff[t - d] : 0;
        __syncthreads();
        loff[t] += v;
        __syncthreads();
    }
    {
        int ex = loff[t] - hist[t];
        __syncthreads();
        loff[t] = ex;
        lcur[t] = ex;
    }
    __syncthreads();
    for (int i = lo + t; i < hi; i += 1024) {
        unsigned s, d;
        if (i < EE) { s = (unsigned)ei[i]; d = (unsigned)ei[EE + i]; }
        else        { s = d = (unsigned)(i - EE); }
        unsigned b = d / NPB;
        int p = atomicAdd(&lcur[b], 1);
        sortedv[p] = (b << 22) | (s << 6) | (d - b * NPB);
    }
    __syncthreads();
    for (int i = t; i < bsize; i += 1024) {
        unsigned v = sortedv[i];
        unsigned b = v >> 22;
        int pp = gbase[b] + i - loff[b];
        if (pp < CAP) tmp[b * CAP + pp] = (int)(v & 0x3FFFFFu);
    }
}

__global__ __launch_bounds__(1024) void k_bscan(const int* __restrict__ bcur,
                                                int* __restrict__ bstart,
                                                int* __restrict__ off) {
    __shared__ int s[NBK];
    int t = threadIdx.x;
    int v0 = bcur[t];
    s[t] = v0;
    __syncthreads();
    for (int d = 1; d < NBK; d <<= 1) {
        int v = (t >= d) ? s[t - d] : 0;
        __syncthreads();
        s[t] += v;
        __syncthreads();
    }
    bstart[t] = s[t] - v0;
    if (t == 0) off[NN] = ETOT;
}

__global__ __launch_bounds__(256) void k_bucket2csr(const int* __restrict__ tmp,
                                                    const int* __restrict__ bcur,
                                                    const int* __restrict__ bstart,
                                                    int* __restrict__ off,
                                                    int* __restrict__ csr,
                                                    int* __restrict__ dstid) {
    __shared__ int sE[CAP];
    __shared__ int lcnt[NPB];
    __shared__ int loff[NPB];
    int b = blockIdx.x, t = threadIdx.x;
    int n0    = b * NPB;
    int bsize = min(bcur[b], CAP);
    int base  = bstart[b];
    if (t < NPB) lcnt[t] = 0;
    for (int i = t; i < bsize; i += 256) sE[i] = tmp[b * CAP + i];
    __syncthreads();
    for (int i = t; i < bsize; i += 256) atomicAdd(&lcnt[sE[i] & 63], 1);
    __syncthreads();
    if (t == 0) {
        int run = 0;
        for (int j = 0; j < NPB; ++j) { loff[j] = run; run += lcnt[j]; }
    }
    __syncthreads();
    if (t < NPB) {
        if (n0 + t < NN) off[n0 + t] = base + loff[t];
        lcnt[t] = loff[t];
    }
    __syncthreads();
    for (int i = t; i < bsize; i += 256) {
        int v   = sE[i];
        int d   = v & 63;
        int pos = base + atomicAdd(&lcnt[d], 1);
        csr[pos]   = v >> 6;
        dstid[pos] = n0 + d;
    }
}

// ---------------- weight packing into MFMA B-fragment order ----------------

__global__ void k_pack(const float* __restrict__ W, ushort* __restrict__ dst,
                       int K, int N) {
    int tid = blockIdx.x * 256 + threadIdx.x;
    int kst = K >> 5;
    int total = (N >> 4) * kst * 64;
    if (tid >= total) return;
    int l = tid & 63;
    int s = (tid >> 6) % kst;
    int T = tid / (kst * 64);
    int m = l & 15, q = l >> 4;
    ushort o[8];
    #pragma unroll
    for (int j = 0; j < 8; ++j)
        o[j] = f2b(W[(s * 32 + q * 8 + j) * N + T * 16 + m]);
    uint4 pk;
    pk.x = (unsigned)o[0] | ((unsigned)o[1] << 16);
    pk.y = (unsigned)o[2] | ((unsigned)o[3] << 16);
    pk.z = (unsigned)o[4] | ((unsigned)o[5] << 16);
    pk.w = (unsigned)o[6] | ((unsigned)o[7] << 16);
    reinterpret_cast<uint4*>(dst)[tid] = pk;
}

// ------- MFMA fused: x@w_in -> +bias -> LN -> GELU -> @W -> hWb + scores -------

__global__ __launch_bounds__(128) void k_infeat(const float* __restrict__ x,
                                                const ushort* __restrict__ Bp1,
                                                const float* __restrict__ bin,
                                                const float* __restrict__ g,
                                                const float* __restrict__ be,
                                                const ushort* __restrict__ Bp2,
                                                const float* __restrict__ asrc,
                                                const float* __restrict__ adst,
                                                ushort* __restrict__ hWb,
                                                float* __restrict__ esrc,
                                                float* __restrict__ edst) {
    __shared__ ushort xbf[2][16 * PADX];
    __shared__ ushort hbf[2][16 * PADH];
    int t = threadIdx.x, w = t >> 6, l = t & 63;
    int m = l & 15, q = l >> 4;
    int n0w = blockIdx.x * 32 + w * 16;
    bool active = (n0w < NN);
    int nb = active ? n0w : 0;

    const float4* x4 = reinterpret_cast<const float4*>(x) + (size_t)nb * 16;
    #pragma unroll
    for (int i = 0; i < 4; ++i) {
        int f4 = l + 64 * i;
        int node = f4 >> 4, c4 = f4 & 15;
        float4 v = x4[f4];
        ushort4 pk = { f2b(v.x), f2b(v.y), f2b(v.z), f2b(v.w) };
        *reinterpret_cast<ushort4*>(&xbf[w][node * PADX + c4 * 4]) = pk;
    }
    __syncthreads();

    const short8* B1 = reinterpret_cast<const short8*>(Bp1);
    floatx4 acc1[8];
    #pragma unroll
    for (int T = 0; T < 8; ++T) acc1[T] = (floatx4){0.f, 0.f, 0.f, 0.f};
    #pragma unroll
    for (int s = 0; s < 2; ++s) {
        short8 a = *reinterpret_cast<const short8*>(&xbf[w][m * PADX + s * 32 + q * 8]);
        #pragma unroll
        for (int T = 0; T < 8; ++T) {
            short8 b = B1[(T * 2 + s) * 64 + l];
            acc1[T] = __builtin_amdgcn_mfma_f32_16x16x32_bf16(a, b, acc1[T], 0, 0, 0);
        }
    }

    float bc[8], gc[8], bec[8];
    #pragma unroll
    for (int T = 0; T < 8; ++T) {
        int c = T * 16 + m;
        bc[T] = bin[c]; gc[T] = g[c]; bec[T] = be[c];
    }
    #pragma unroll
    for (int j = 0; j < 4; ++j) {
        float s1 = 0.f, s2 = 0.f;
        #pragma unroll
        for (int T = 0; T < 8; ++T) {
            float v = acc1[T][j] + bc[T];
            s1 += v; s2 = fmaf(v, v, s2);
        }
        #pragma unroll
        for (int mk = 1; mk < 16; mk <<= 1) {
            s1 += __shfl_xor(s1, mk, 64);
            s2 += __shfl_xor(s2, mk, 64);
        }
        float mu = s1 * (1.f / 128.f);
        float var = s2 * (1.f / 128.f) - mu * mu;
        float rs = rsqrtf(var + 1e-5f);
        #pragma unroll
        for (int T = 0; T < 8; ++T) {
            float v = acc1[T][j] + bc[T];
            float y = (v - mu) * rs * gc[T] + bec[T];
            hbf[w][(q * 4 + j) * PADH + T * 16 + m] = f2b(gelu_f(y));
        }
    }
    __syncthreads();

    const short8* B2 = reinterpret_cast<const short8*>(Bp2);
    floatx4 acc2[8];
    #pragma unroll
    for (int T = 0; T < 8; ++T) acc2[T] = (floatx4){0.f, 0.f, 0.f, 0.f};
    #pragma unroll
    for (int s = 0; s < 4; ++s) {
        short8 a = *reinterpret_cast<const short8*>(&hbf[w][m * PADH + s * 32 + q * 8]);
        #pragma unroll
        for (int T = 0; T < 8; ++T) {
            short8 b = B2[(T * 4 + s) * 64 + l];
            acc2[T] = __builtin_amdgcn_mfma_f32_16x16x32_bf16(a, b, acc2[T], 0, 0, 0);
        }
    }

    float as_[8], ad_[8];
    #pragma unroll
    for (int T = 0; T < 8; ++T) {
        int c = T * 16 + m;
        as_[T] = asrc[c]; ad_[T] = adst[c];
    }
    if (active) {
        #pragma unroll
        for (int j = 0; j < 4; ++j)
            #pragma unroll
            for (int T = 0; T < 8; ++T)
                hWb[(size_t)(n0w + q * 4 + j) * HID + T * 16 + m] = f2b(acc2[T][j]);
    }
    #pragma unroll
    for (int j = 0; j < 4; ++j) {
        #pragma unroll
        for (int h = 0; h < 4; ++h) {
            float v1 = fmaf(acc2[2 * h][j], as_[2 * h], acc2[2 * h + 1][j] * as_[2 * h + 1]);
            float v2 = fmaf(acc2[2 * h][j], ad_[2 * h], acc2[2 * h + 1][j] * ad_[2 * h + 1]);
            #pragma unroll
            for (int mk = 1; mk < 16; mk <<= 1) {
                v1 += __shfl_xor(v1, mk, 64);
                v2 += __shfl_xor(v2, mk, 64);
            }
            if (m == 0 && active) {
                esrc[(n0w + q * 4 + j) * 4 + h] = v1;
                edst[(n0w + q * 4 + j) * 4 + h] = v2;
            }
        }
    }
}

// ------- MFMA fused layer-2: LN(gout) -> GELU -> @W2 -> hWb + scores -------

__global__ __launch_bounds__(128) void k_feat(const float* __restrict__ hin,
                                              const float* __restrict__ g,
                                              const float* __restrict__ be,
                                              const ushort* __restrict__ Bp2,
                                              const float* __restrict__ asrc,
                                              const float* __restrict__ adst,
                                              ushort* __restrict__ hWb,
                                              float* __restrict__ esrc,
                                              float* __restrict__ edst) {
    __shared__ ushort hbf[2][16 * PADH];
    int t = threadIdx.x, w = t >> 6, l = t & 63;
    int m = l & 15, q = l >> 4;
    int n0w = blockIdx.x * 32 + w * 16;
    bool active = (n0w < NN);
    int nb = active ? n0w : 0;

    const float4* h4g = reinterpret_cast<const float4*>(hin) + (size_t)nb * 32;
    const float4* g4  = reinterpret_cast<const float4*>(g);
    const float4* be4 = reinterpret_cast<const float4*>(be);
    #pragma unroll
    for (int i = 0; i < 8; ++i) {
        int f4 = l + 64 * i;
        int node = f4 >> 5, c4 = f4 & 31;
        float4 v = h4g[f4];
        float s1 = v.x + v.y + v.z + v.w;
        float s2 = fmaf(v.x, v.x, fmaf(v.y, v.y, fmaf(v.z, v.z, v.w * v.w)));
        #pragma unroll
        for (int mk = 1; mk < 32; mk <<= 1) {
            s1 += __shfl_xor(s1, mk, 64);
            s2 += __shfl_xor(s2, mk, 64);
        }
        float mu = s1 * (1.f / 128.f);
        float var = s2 * (1.f / 128.f) - mu * mu;
        float rs = rsqrtf(var + 1e-5f);
        float4 gg = g4[c4], bb = be4[c4];
        ushort4 pk;
        pk.x = f2b(gelu_f((v.x - mu) * rs * gg.x + bb.x));
        pk.y = f2b(gelu_f((v.y - mu) * rs * gg.y + bb.y));
        pk.z = f2b(gelu_f((v.z - mu) * rs * gg.z + bb.z));
        pk.w = f2b(gelu_f((v.w - mu) * rs * gg.w + bb.w));
        *reinterpret_cast<ushort4*>(&hbf[w][node * PADH + c4 * 4]) = pk;
    }
    __syncthreads();

    const short8* B2 = reinterpret_cast<const short8*>(Bp2);
    floatx4 acc2[8];
    #pragma unroll
    for (int T = 0; T < 8; ++T) acc2[T] = (floatx4){0.f, 0.f, 0.f, 0.f};
    #pragma unroll
    for (int s = 0; s < 4; ++s) {
        short8 a = *reinterpret_cast<const short8*>(&hbf[w][m * PADH + s * 32 + q * 8]);
        #pragma unroll
        for (int T = 0; T < 8; ++T) {
            short8 b = B2[(T * 4 + s) * 64 + l];
            acc2[T] = __builtin_amdgcn_mfma_f32_16x16x32_bf16(a, b, acc2[T], 0, 0, 0);
        }
    }

    float as_[8], ad_[8];
    #pragma unroll
    for (int T = 0; T < 8; ++T) {
        int c = T * 16 + m;
        as_[T] = asrc[c]; ad_[T] = adst[c];
    }
    if (active) {
        #pragma unroll
        for (int j = 0; j < 4; ++j)
            #pragma unroll
            for (int T = 0; T < 8; ++T)
                hWb[(size_t)(n0w + q * 4 + j) * HID + T * 16 + m] = f2b(acc2[T][j]);
    }
    #pragma unroll
    for (int j = 0; j < 4; ++j) {
        #pragma unroll
        for (int h = 0; h < 4; ++h) {
            float v1 = fmaf(acc2[2 * h][j], as_[2 * h], acc2[2 * h + 1][j] * as_[2 * h + 1]);
            float v2 = fmaf(acc2[2 * h][j], ad_[2 * h], acc2[2 * h + 1][j] * ad_[2 * h + 1]);
            #pragma unroll
            for (int mk = 1; mk < 16; mk <<= 1) {
                v1 += __shfl_xor(v1, mk, 64);
                v2 += __shfl_xor(v2, mk, 64);
            }
            if (m == 0 && active) {
                esrc[(n0w + q * 4 + j) * 4 + h] = v1;
                edst[(n0w + q * 4 + j) * 4 + h] = v2;
            }
        }
    }
}

// ------- bf16 rows -> fp8 e4m3 rows (gather table for k_gat) -------

__global__ __launch_bounds__(256) void k_cvt8(const ushort* __restrict__ hWb,
                                              uint* __restrict__ hW8) {
    int tid = blockIdx.x * 256 + threadIdx.x;    // one uint2 (8 cols) per thread
    if (tid >= NN * HID / 8) return;
    uint4 v = reinterpret_cast<const uint4*>(hWb)[tid];
    float f0 = __uint_as_float(v.x << 16), f1 = __uint_as_float(v.x & 0xffff0000u);
    float f2 = __uint_as_float(v.y << 16), f3 = __uint_as_float(v.y & 0xffff0000u);
    float f4 = __uint_as_float(v.z << 16), f5 = __uint_as_float(v.z & 0xffff0000u);
    float f6 = __uint_as_float(v.w << 16), f7 = __uint_as_float(v.w & 0xffff0000u);
    int lo = __builtin_amdgcn_cvt_pk_fp8_f32(f0, f1, 0, false);
    lo     = __builtin_amdgcn_cvt_pk_fp8_f32(f2, f3, lo, true);
    int hi = __builtin_amdgcn_cvt_pk_fp8_f32(f4, f5, 0, false);
    hi     = __builtin_amdgcn_cvt_pk_fp8_f32(f6, f7, hi, true);
    uint2 pk = { (unsigned)lo, (unsigned)hi };
    reinterpret_cast<uint2*>(hW8)[tid] = pk;
}

// ------- edge-parallel attention weights -------

__global__ __launch_bounds__(256) void k_edgew(const int* __restrict__ csr,
                                               const int* __restrict__ dstid,
                                               const float* __restrict__ esrc,
                                               const float* __restrict__ edst,
                                               ushort* __restrict__ wexp) {
    int i = blockIdx.x * 256 + threadIdx.x;
    if (i >= ETOT) return;
    int s = csr[i], d = dstid[i];
    float4 es = reinterpret_cast<const float4*>(esrc)[s];
    float4 ed = reinterpret_cast<const float4*>(edst)[d];
    float e0 = es.x + ed.x, e1 = es.y + ed.y, e2 = es.z + ed.z, e3 = es.w + ed.w;
    e0 = __expf(fmaxf(e0, 0.2f * e0));
    e1 = __expf(fmaxf(e1, 0.2f * e1));
    e2 = __expf(fmaxf(e2, 0.2f * e2));
    e3 = __expf(fmaxf(e3, 0.2f * e3));
    ushort4 pk = { f2b(e0), f2b(e1), f2b(e2), f2b(e3) };
    reinterpret_cast<ushort4*>(wexp)[i] = pk;
}

// ------- GAT aggregate v6: R8 pipeline, fp8 rows (8B per 8 cols per lane) -------
// 128 thr = 2 waves x 4 edge-slots x 16 lane-groups (uint2 = 8 fp8 cols per lane).
// Body: issue rows it+2,it+3 + indices it+4,it+5, then FMA batches it,it+1.

__global__ __launch_bounds__(128) void k_gat(const uint* __restrict__ hW8,
                                             const ushort* __restrict__ wexp,
                                             const int* __restrict__ off,
                                             const int* __restrict__ csr,
                                             const float* __restrict__ bg,
                                             float* __restrict__ out) {
    __shared__ float redA[16][8];
    __shared__ float redD[16];
    int n = blockIdx.x, t = threadIdx.x;
    int wv = t >> 6, l = t & 63;
    int slot = l >> 4;          // lane bits 4-5 = edge slot
    int q    = l & 15;          // col group: cols 8q..8q+7
    int hq   = q >> 2;          // head of those cols
    int o0 = off[n], o1 = off[n + 1];
    const uint2* hw2 = reinterpret_cast<const uint2*>(hW8);
    float acc[8] = {0.f, 0.f, 0.f, 0.f, 0.f, 0.f, 0.f, 0.f};
    float dsum = 0.f;
    int nIter = (o1 - o0 + 15) >> 4;       // 16 edges per body (8 per wave)
    int e = o0 + wv * 4 + slot;            // this lane's batch-0 edge

    // prologue: indices for batches 0..3, rows for 0..1
    int eA = min(e,      ETOT - 1);
    int eB = min(e + 8,  ETOT - 1);
    int eC = min(e + 16, ETOT - 1);
    int eD = min(e + 24, ETOT - 1);
    int    srcA = csr[eA]; ushort ubA = wexp[eA * 4 + hq];
    int    srcB = csr[eB]; ushort ubB = wexp[eB * 4 + hq];
    int    srcC = csr[eC]; ushort ubC = wexp[eC * 4 + hq];
    int    srcD = csr[eD]; ushort ubD = wexp[eD * 4 + hq];
    uint2  rA = hw2[(size_t)srcA * 16 + q];
    uint2  rB = hw2[(size_t)srcB * 16 + q];

    for (int it = 0; it < nIter; ++it) {
        // issue rows it+2, it+3 (indices loaded 2 bodies ago — no wait chain)
        uint2 rC = hw2[(size_t)srcC * 16 + q];
        uint2 rD = hw2[(size_t)srcD * 16 + q];
        // prefetch indices it+4, it+5
        int eE = min(e + 32, ETOT - 1);
        int eF = min(e + 40, ETOT - 1);
        int    srcE = csr[eE]; ushort ubE = wexp[eE * 4 + hq];
        int    srcF = csr[eF]; ushort ubF = wexp[eF * 4 + hq];
        // process batch it (rA) and it+1 (rB)
        float wa = (e     < o1) ? __uint_as_float(((unsigned)ubA) << 16) : 0.f;
        float wb = (e + 8 < o1) ? __uint_as_float(((unsigned)ubB) << 16) : 0.f;
        {
            auto p0 = __builtin_amdgcn_cvt_pk_f32_fp8(rA.x, false);
            auto p1 = __builtin_amdgcn_cvt_pk_f32_fp8(rA.x, true);
            auto p2 = __builtin_amdgcn_cvt_pk_f32_fp8(rA.y, false);
            auto p3 = __builtin_amdgcn_cvt_pk_f32_fp8(rA.y, true);
            acc[0] = fmaf(wa, p0[0], acc[0]);
            acc[1] = fmaf(wa, p0[1], acc[1]);
            acc[2] = fmaf(wa, p1[0], acc[2]);
            acc[3] = fmaf(wa, p1[1], acc[3]);
            acc[4] = fmaf(wa, p2[0], acc[4]);
            acc[5] = fmaf(wa, p2[1], acc[5]);
            acc[6] = fmaf(wa, p3[0], acc[6]);
            acc[7] = fmaf(wa, p3[1], acc[7]);
        }
        {
            auto p0 = __builtin_amdgcn_cvt_pk_f32_fp8(rB.x, false);
            auto p1 = __builtin_amdgcn_cvt_pk_f32_fp8(rB.x, true);
            auto p2 = __builtin_amdgcn_cvt_pk_f32_fp8(rB.y, false);
            auto p3 = __builtin_amdgcn_cvt_pk_f32_fp8(rB.y, true);
            acc[0] = fmaf(wb, p0[0], acc[0]);
            acc[1] = fmaf(wb, p0[1], acc[1]);
            acc[2] = fmaf(wb, p1[0], acc[2]);
            acc[3] = fmaf(wb, p1[1], acc[3]);
            acc[4] = fmaf(wb, p2[0], acc[4]);
            acc[5] = fmaf(wb, p2[1], acc[5]);
            acc[6] = fmaf(wb, p3[0], acc[6]);
            acc[7] = fmaf(wb, p3[1], acc[7]);
        }
        dsum += wa + wb;
        e += 16;
        rA = rC; rB = rD;
        srcC = srcE; srcD = srcF;
        ubA = ubC; ubB = ubD; ubC = ubE; ubD = ubF;
    }
    // reduce across the 4 edge slots (lane bits 4 and 5)
    #pragma unroll
    for (int mk = 16; mk <= 32; mk <<= 1) {
        #pragma unroll
        for (int j = 0; j < 8; ++j) acc[j] += __shfl_xor(acc[j], mk, 64);
        dsum += __shfl_xor(dsum, mk, 64);
    }
    if (wv == 1 && l < 16) {
        #pragma unroll
        for (int j = 0; j < 8; ++j) redA[l][j] = acc[j];
        redD[l] = dsum;
    }
    __syncthreads();
    if (wv == 0 && l < 16) {
        float inv = 1.0f / (dsum + redD[l]);
        float4 r0, r1;
        r0.x = (acc[0] + redA[l][0]) * inv + bg[l * 8 + 0];
        r0.y = (acc[1] + redA[l][1]) * inv + bg[l * 8 + 1];
        r0.z = (acc[2] + redA[l][2]) * inv + bg[l * 8 + 2];
        r0.w = (acc[3] + redA[l][3]) * inv + bg[l * 8 + 3];
        r1.x = (acc[4] + redA[l][4]) * inv + bg[l * 8 + 4];
        r1.y = (acc[5] + redA[l][5]) * inv + bg[l * 8 + 5];
        r1.z = (acc[6] + redA[l][6]) * inv + bg[l * 8 + 6];
        r1.w = (acc[7] + redA[l][7]) * inv + bg[l * 8 + 7];
        float4* op = reinterpret_cast<float4*>(out + (size_t)n * HID + l * 8);
        op[0] = r0; op[1] = r1;
    }
}

// ---------------- output linear: fp32 register-tiled 4 nodes x 4 cols ----------------

__global__ __launch_bounds__(64) void k_out(const float* __restrict__ h,
                                            const float* __restrict__ w,
                                            const float* __restrict__ b,
                                            float* __restrict__ out) {
    __shared__ __align__(16) float hr[16 * 132];
    int t = threadIdx.x, n0 = blockIdx.x * 16;
    const float4* h4g = reinterpret_cast<const float4*>(h) + (size_t)n0 * 32;
    float4* hr4 = reinterpret_cast<float4*>(hr);
    #pragma unroll
    for (int i = 0; i < 8; ++i) {
        int f4 = t + 64 * i;
        hr4[(f4 >> 5) * 33 + (f4 & 31)] = h4g[f4];
    }
    __syncthreads();
    int cg = t & 15, ng = t >> 4;
    const float4* w4 = reinterpret_cast<const float4*>(w);
    float4 bb = reinterpret_cast<const float4*>(b)[cg];
    float4 acc[4] = {bb, bb, bb, bb};
    for (int k4 = 0; k4 < 32; ++k4) {
        float4 w0 = w4[(k4 * 4 + 0) * 16 + cg];
        float4 w1 = w4[(k4 * 4 + 1) * 16 + cg];
        float4 w2 = w4[(k4 * 4 + 2) * 16 + cg];
        float4 w3 = w4[(k4 * 4 + 3) * 16 + cg];
        #pragma unroll
        for (int r = 0; r < 4; ++r) {
            float4 hv = hr4[(ng * 4 + r) * 33 + k4];
            acc[r].x = fmaf(hv.x, w0.x, fmaf(hv.y, w1.x, fmaf(hv.z, w2.x, fmaf(hv.w, w3.x, acc[r].x))));
            acc[r].y = fmaf(hv.x, w0.y, fmaf(hv.y, w1.y, fmaf(hv.z, w2.y, fmaf(hv.w, w3.y, acc[r].y))));
            acc[r].z = fmaf(hv.x, w0.z, fmaf(hv.y, w1.z, fmaf(hv.z, w2.z, fmaf(hv.w, w3.z, acc[r].z))));
            acc[r].w = fmaf(hv.x, w0.w, fmaf(hv.y, w1.w, fmaf(hv.z, w2.w, fmaf(hv.w, w3.w, acc[r].w))));
        }
    }
    float4* o4 = reinterpret_cast<float4*>(out) + (size_t)n0 * 16;
    #pragma unroll
    for (int r = 0; r < 4; ++r) o4[(ng * 4 + r) * 16 + cg] = acc[r];
}

extern "C" void kernel_launch(void* const* d_in, const int* in_sizes, int n_in,
                              void* d_out, int out_size, void* d_ws, size_t ws_size,
                              hipStream_t stream) {
    const float* x    = (const float*)d_in[0];
    const int*   ei   = (const int*)  d_in[1];
    const float* w_in = (const float*)d_in[2];
    const float* b_in = (const float*)d_in[3];
    const float* g1   = (const float*)d_in[4];
    const float* be1  = (const float*)d_in[5];
    const float* W1   = (const float*)d_in[6];
    const float* as1  = (const float*)d_in[7];
    const float* ad1  = (const float*)d_in[8];
    const float* bg1  = (const float*)d_in[9];
    const float* g2   = (const float*)d_in[10];
    const float* be2  = (const float*)d_in[11];
    const float* W2   = (const float*)d_in[12];
    const float* as2  = (const float*)d_in[13];
    const float* ad2  = (const float*)d_in[14];
    const float* bg2  = (const float*)d_in[15];
    const float* w_o  = (const float*)d_in[16];
    const float* b_o  = (const float*)d_in[17];
    float* out = (float*)d_out;

    char* p = (char*)d_ws;
    auto take = [&](size_t bytes) {
        void* r = p;
        p += (bytes + 255) & ~(size_t)255;
        return r;
    };
    float*  gout  = (float*)take((size_t)NN * HID * 4);
    float*  h2    = (float*)take((size_t)NN * HID * 4);
    ushort* hWb   = (ushort*)take((size_t)NN * HID * 2);
    uint*   hW8   = (uint*)take((size_t)NN * HID);       // fp8 gather table
    float*  esrc  = (float*)take((size_t)NN * 4 * 4);
    float*  edst  = (float*)take((size_t)NN * 4 * 4);
    int*    off   = (int*)take((size_t)(NN + 1) * 4);
    int*    csr   = (int*)take((size_t)ETOT * 4);
    int*    dstid = (int*)take((size_t)ETOT * 4);
    size_t ovl = (size_t)ETOT * 8;
    size_t tsz = (size_t)NBK * CAP * 4;
    ushort* wexp  = (ushort*)take(ovl > tsz ? ovl : tsz);
    int*    tmp   = (int*)wexp;
    int*    bcur  = (int*)take((size_t)NBK * 4);
    int*    bstart= (int*)take((size_t)NBK * 4);
    ushort* Bp1   = (ushort*)take((size_t)1024 * 16);
    ushort* BpW1  = (ushort*)take((size_t)2048 * 16);
    ushort* BpW2  = (ushort*)take((size_t)2048 * 16);

    k_pack<<<4, 256, 0, stream>>>(w_in, Bp1, 64, 128);
    k_pack<<<8, 256, 0, stream>>>(W1, BpW1, 128, 128);
    k_pack<<<8, 256, 0, stream>>>(W2, BpW2, 128, 128);

    k_zero      <<<(NBK + 255) / 256, 256, 0, stream>>>(bcur);
    k_bucket    <<<BBLK, 1024, 0, stream>>>(ei, bcur, tmp);
    k_bscan     <<<1, NBK, 0, stream>>>(bcur, bstart, off);
    k_bucket2csr<<<NBK, 256, 0, stream>>>(tmp, bcur, bstart, off, csr, dstid);

    int gfeat = (NN + 31) / 32;
    int gcvt  = (NN * HID / 8 + 255) / 256;
    k_infeat<<<gfeat, 128, 0, stream>>>(x, Bp1, b_in, g1, be1, BpW1, as1, ad1, hWb, esrc, edst);
    k_cvt8  <<<gcvt, 256, 0, stream>>>(hWb, hW8);
    k_edgew <<<(ETOT + 255) / 256, 256, 0, stream>>>(csr, dstid, esrc, edst, wexp);
    k_gat   <<<NN, 128, 0, stream>>>(hW8, wexp, off, csr, bg1, gout);
    k_feat  <<<gfeat, 128, 0, stream>>>(gout, g2, be2, BpW2, as2, ad2, hWb, esrc, edst);
    k_cvt8  <<<gcvt, 256, 0, stream>>>(hWb, hW8);
    k_edgew <<<(ETOT + 255) / 256, 256, 0, stream>>>(csr, dstid, esrc, edst, wexp);
    k_gat   <<<NN, 128, 0, stream>>>(hW8, wexp, off, csr, bg2, h2);
    k_out   <<<NN / 16, 64, 0, stream>>>(h2, w_o, b_o, out);
}

// Round 10
// 304.403 us; speedup vs baseline: 1.4567x; 1.0641x over previous
//
#include <hip/hip_runtime.h>
#include <hip/hip_bf16.h>
#include <math.h>

#define NN   50000
#define EE   1600000
#define ETOT (EE + NN)
#define HID  128
#define INF_ 64
#define OUTF 64

// bucketed CSR build
#define NBK  1024   // buckets (contiguous dst ranges)
#define NPB  49     // nodes per bucket (1024*49 = 50176 >= NN)
#define CAP  3072   // per-bucket capacity; mean ~1617, 1.9x headroom
#define BBLK 256    // blocks for k_bucket
#define CHUNK ((ETOT + BBLK - 1) / BBLK)   // 6446 edges per block

#define PADX 72     // xbf row stride (ushorts), 144 B (16B-aligned)
#define PADH 136    // hbf row stride (ushorts), 272 B (16B-aligned)

typedef short  short8  __attribute__((ext_vector_type(8)));
typedef float  floatx4 __attribute__((ext_vector_type(4)));
typedef float  floatx2 __attribute__((ext_vector_type(2)));

__device__ __forceinline__ ushort f2b(float f) {
    __hip_bfloat16 h = __float2bfloat16(f);
    return *reinterpret_cast<ushort*>(&h);
}

// fast tanh-gelu: gelu(x) = x * t/(t+1), t = exp(2u), u = 0.79788456*(x+0.044715x^3)
__device__ __forceinline__ float gelu_f(float x) {
    float x2 = x * x;
    float u  = 0.7978845608f * fmaf(0.044715f * x2, x, x);
    u = fminf(u, 40.f);
    float t = __expf(2.f * u);
    return x * t / (t + 1.f);
}

// ---------------- CSR build (bucketed counting sort) ----------------

__global__ __launch_bounds__(1024) void k_bucket(const int* __restrict__ ei,
                                                 int* bcur, int* __restrict__ tmp) {
    __shared__ unsigned sortedv[CHUNK];
    __shared__ int hist[NBK], gbase[NBK], loff[NBK], lcur[NBK];
    int t = threadIdx.x;
    int lo = blockIdx.x * CHUNK;
    int hi = min(lo + CHUNK, ETOT);
    int bsize = hi - lo;
    hist[t] = 0;
    __syncthreads();
    for (int i = lo + t; i < hi; i += 1024) {
        int d = (i < EE) ? ei[EE + i] : i - EE;
        atomicAdd(&hist[d / NPB], 1);
    }
    __syncthreads();
    {
        int c = hist[t];
        gbase[t] = (c > 0) ? atomicAdd(&bcur[t], c) : 0;
        loff[t] = c;
    }
    __syncthreads();
    for (int d = 1; d < NBK; d <<= 1) {
        int v = (t >= d) ? loff[t - d] : 0;
        __syncthreads();
        loff[t] += v;
        __syncthreads();
    }
    {
        int ex = loff[t] - hist[t];
        __syncthreads();
        loff[t] = ex;
        lcur[t] = ex;
    }
    __syncthreads();
    for (int i = lo + t; i < hi; i += 1024) {
        unsigned s, d;
        if (i < EE) { s = (unsigned)ei[i]; d = (unsigned)ei[EE + i]; }
        else        { s = d = (unsigned)(i - EE); }
        unsigned b = d / NPB;
        int p = atomicAdd(&lcur[b], 1);
        sortedv[p] = (b << 22) | (s << 6) | (d - b * NPB);
    }
    __syncthreads();
    for (int i = t; i < bsize; i += 1024) {
        unsigned v = sortedv[i];
        unsigned b = v >> 22;
        int pp = gbase[b] + i - loff[b];
        if (pp < CAP) tmp[b * CAP + pp] = (int)(v & 0x3FFFFFu);
    }
}

// scan of bucket sizes; also zeroes the csr pad region (ETOT..ETOT+63)
__global__ __launch_bounds__(1024) void k_bscan(const int* __restrict__ bcur,
                                                int* __restrict__ bstart,
                                                int* __restrict__ off,
                                                int* __restrict__ csr) {
    __shared__ int s[NBK];
    int t = threadIdx.x;
    int v0 = bcur[t];
    s[t] = v0;
    __syncthreads();
    for (int d = 1; d < NBK; d <<= 1) {
        int v = (t >= d) ? s[t - d] : 0;
        __syncthreads();
        s[t] += v;
        __syncthreads();
    }
    bstart[t] = s[t] - v0;
    if (t == 0) off[NN] = ETOT;
    if (t < 64) csr[ETOT + t] = 0;   // pad: k_gat reads past o1 unclamped
}

__global__ __launch_bounds__(256) void k_bucket2csr(const int* __restrict__ tmp,
                                                    const int* __restrict__ bcur,
                                                    const int* __restrict__ bstart,
                                                    int* __restrict__ off,
                                                    int* __restrict__ csr,
                                                    int* __restrict__ dstid) {
    __shared__ int sE[CAP];
    __shared__ int lcnt[NPB];
    __shared__ int loff[NPB];
    int b = blockIdx.x, t = threadIdx.x;
    int n0    = b * NPB;
    int bsize = min(bcur[b], CAP);
    int base  = bstart[b];
    if (t < NPB) lcnt[t] = 0;
    for (int i = t; i < bsize; i += 256) sE[i] = tmp[b * CAP + i];
    __syncthreads();
    for (int i = t; i < bsize; i += 256) atomicAdd(&lcnt[sE[i] & 63], 1);
    __syncthreads();
    if (t == 0) {
        int run = 0;
        for (int j = 0; j < NPB; ++j) { loff[j] = run; run += lcnt[j]; }
    }
    __syncthreads();
    if (t < NPB) {
        if (n0 + t < NN) off[n0 + t] = base + loff[t];
        lcnt[t] = loff[t];
    }
    __syncthreads();
    for (int i = t; i < bsize; i += 256) {
        int v   = sE[i];
        int d   = v & 63;
        int pos = base + atomicAdd(&lcnt[d], 1);
        csr[pos]   = v >> 6;
        dstid[pos] = n0 + d;
    }
}

// ---- combined weight packing (w_in, W1, W2) + bcur zeroing: one launch ----
// frag index (T*kst + s)*64 + l holds B[k = s*32 + (l>>4)*8 + j][n = T*16 + (l&15)]

__global__ void k_packall(const float* __restrict__ w_in, const float* __restrict__ W1,
                          const float* __restrict__ W2, ushort* __restrict__ Bp1,
                          ushort* __restrict__ BpW1, ushort* __restrict__ BpW2,
                          int* __restrict__ bcur) {
    int tid = blockIdx.x * 256 + threadIdx.x;
    if (tid < NBK) bcur[tid] = 0;
    const float* W; ushort* dst; int K, id;
    if (tid < 1024)      { W = w_in; dst = Bp1;  K = 64;  id = tid; }
    else if (tid < 3072) { W = W1;   dst = BpW1; K = 128; id = tid - 1024; }
    else if (tid < 5120) { W = W2;   dst = BpW2; K = 128; id = tid - 3072; }
    else return;
    int kst = K >> 5;
    int l = id & 63;
    int s = (id >> 6) % kst;
    int T = id / (kst * 64);
    int m = l & 15, q = l >> 4;
    ushort o[8];
    #pragma unroll
    for (int j = 0; j < 8; ++j)
        o[j] = f2b(W[(s * 32 + q * 8 + j) * 128 + T * 16 + m]);
    uint4 pk;
    pk.x = (unsigned)o[0] | ((unsigned)o[1] << 16);
    pk.y = (unsigned)o[2] | ((unsigned)o[3] << 16);
    pk.z = (unsigned)o[4] | ((unsigned)o[5] << 16);
    pk.w = (unsigned)o[6] | ((unsigned)o[7] << 16);
    reinterpret_cast<uint4*>(dst)[id] = pk;
}

// ---- shared epilogue helper: stage acc2 (bf16) in LDS, pack fp8 rows, store ----
// lane l packs row l>>2, 32-col chunk l&3 -> two uint4 stores.
__device__ __forceinline__ void pack_store_fp8(ushort* hbfw, int l, int n0w, bool active,
                                               uint* __restrict__ hW8) {
    if (!active) return;
    int row = l >> 2, ch = l & 3;
    uint ov[8];
    #pragma unroll
    for (int u = 0; u < 8; ++u) {
        int c0 = ch * 32 + u * 4;
        float f0 = __uint_as_float((uint)hbfw[row * PADH + c0 + 0] << 16);
        float f1 = __uint_as_float((uint)hbfw[row * PADH + c0 + 1] << 16);
        float f2 = __uint_as_float((uint)hbfw[row * PADH + c0 + 2] << 16);
        float f3 = __uint_as_float((uint)hbfw[row * PADH + c0 + 3] << 16);
        int pk = __builtin_amdgcn_cvt_pk_fp8_f32(f0, f1, 0, false);
        pk     = __builtin_amdgcn_cvt_pk_fp8_f32(f2, f3, pk, true);
        ov[u] = (uint)pk;
    }
    uint4* dst = reinterpret_cast<uint4*>(hW8 + (size_t)(n0w + row) * 32 + ch * 8);
    dst[0] = make_uint4(ov[0], ov[1], ov[2], ov[3]);
    dst[1] = make_uint4(ov[4], ov[5], ov[6], ov[7]);
}

// ------- MFMA fused: x@w_in -> +bias -> LN -> GELU -> @W -> fp8 rows + scores -------

__global__ __launch_bounds__(128) void k_infeat(const float* __restrict__ x,
                                                const ushort* __restrict__ Bp1,
                                                const float* __restrict__ bin,
                                                const float* __restrict__ g,
                                                const float* __restrict__ be,
                                                const ushort* __restrict__ Bp2,
                                                const float* __restrict__ asrc,
                                                const float* __restrict__ adst,
                                                uint* __restrict__ hW8,
                                                float* __restrict__ esrc,
                                                float* __restrict__ edst) {
    __shared__ ushort xbf[2][16 * PADX];
    __shared__ ushort hbf[2][16 * PADH];
    int t = threadIdx.x, w = t >> 6, l = t & 63;
    int m = l & 15, q = l >> 4;
    int n0w = blockIdx.x * 32 + w * 16;
    bool active = (n0w < NN);
    int nb = active ? n0w : 0;

    const float4* x4 = reinterpret_cast<const float4*>(x) + (size_t)nb * 16;
    #pragma unroll
    for (int i = 0; i < 4; ++i) {
        int f4 = l + 64 * i;
        int node = f4 >> 4, c4 = f4 & 15;
        float4 v = x4[f4];
        ushort4 pk = { f2b(v.x), f2b(v.y), f2b(v.z), f2b(v.w) };
        *reinterpret_cast<ushort4*>(&xbf[w][node * PADX + c4 * 4]) = pk;
    }
    __syncthreads();

    const short8* B1 = reinterpret_cast<const short8*>(Bp1);
    floatx4 acc1[8];
    #pragma unroll
    for (int T = 0; T < 8; ++T) acc1[T] = (floatx4){0.f, 0.f, 0.f, 0.f};
    #pragma unroll
    for (int s = 0; s < 2; ++s) {
        short8 a = *reinterpret_cast<const short8*>(&xbf[w][m * PADX + s * 32 + q * 8]);
        #pragma unroll
        for (int T = 0; T < 8; ++T) {
            short8 b = B1[(T * 2 + s) * 64 + l];
            acc1[T] = __builtin_amdgcn_mfma_f32_16x16x32_bf16(a, b, acc1[T], 0, 0, 0);
        }
    }

    float bc[8], gc[8], bec[8];
    #pragma unroll
    for (int T = 0; T < 8; ++T) {
        int c = T * 16 + m;
        bc[T] = bin[c]; gc[T] = g[c]; bec[T] = be[c];
    }
    #pragma unroll
    for (int j = 0; j < 4; ++j) {
        float s1 = 0.f, s2 = 0.f;
        #pragma unroll
        for (int T = 0; T < 8; ++T) {
            float v = acc1[T][j] + bc[T];
            s1 += v; s2 = fmaf(v, v, s2);
        }
        #pragma unroll
        for (int mk = 1; mk < 16; mk <<= 1) {
            s1 += __shfl_xor(s1, mk, 64);
            s2 += __shfl_xor(s2, mk, 64);
        }
        float mu = s1 * (1.f / 128.f);
        float var = s2 * (1.f / 128.f) - mu * mu;
        float rs = rsqrtf(var + 1e-5f);
        #pragma unroll
        for (int T = 0; T < 8; ++T) {
            float v = acc1[T][j] + bc[T];
            float y = (v - mu) * rs * gc[T] + bec[T];
            hbf[w][(q * 4 + j) * PADH + T * 16 + m] = f2b(gelu_f(y));
        }
    }
    __syncthreads();

    const short8* B2 = reinterpret_cast<const short8*>(Bp2);
    floatx4 acc2[8];
    #pragma unroll
    for (int T = 0; T < 8; ++T) acc2[T] = (floatx4){0.f, 0.f, 0.f, 0.f};
    #pragma unroll
    for (int s = 0; s < 4; ++s) {
        short8 a = *reinterpret_cast<const short8*>(&hbf[w][m * PADH + s * 32 + q * 8]);
        #pragma unroll
        for (int T = 0; T < 8; ++T) {
            short8 b = B2[(T * 4 + s) * 64 + l];
            acc2[T] = __builtin_amdgcn_mfma_f32_16x16x32_bf16(a, b, acc2[T], 0, 0, 0);
        }
    }

    // restage acc2 as bf16 rows, pack fp8, store (replaces bf16 hWb + k_cvt8)
    __syncthreads();
    #pragma unroll
    for (int j = 0; j < 4; ++j)
        #pragma unroll
        for (int T = 0; T < 8; ++T)
            hbf[w][(q * 4 + j) * PADH + T * 16 + m] = f2b(acc2[T][j]);
    __syncthreads();
    pack_store_fp8(hbf[w], l, n0w, active, hW8);

    float as_[8], ad_[8];
    #pragma unroll
    for (int T = 0; T < 8; ++T) {
        int c = T * 16 + m;
        as_[T] = asrc[c]; ad_[T] = adst[c];
    }
    #pragma unroll
    for (int j = 0; j < 4; ++j) {
        #pragma unroll
        for (int h = 0; h < 4; ++h) {
            float v1 = fmaf(acc2[2 * h][j], as_[2 * h], acc2[2 * h + 1][j] * as_[2 * h + 1]);
            float v2 = fmaf(acc2[2 * h][j], ad_[2 * h], acc2[2 * h + 1][j] * ad_[2 * h + 1]);
            #pragma unroll
            for (int mk = 1; mk < 16; mk <<= 1) {
                v1 += __shfl_xor(v1, mk, 64);
                v2 += __shfl_xor(v2, mk, 64);
            }
            if (m == 0 && active) {
                esrc[(n0w + q * 4 + j) * 4 + h] = v1;
                edst[(n0w + q * 4 + j) * 4 + h] = v2;
            }
        }
    }
}

// ------- MFMA fused layer-2: LN(gout) -> GELU -> @W2 -> fp8 rows + scores -------

__global__ __launch_bounds__(128) void k_feat(const float* __restrict__ hin,
                                              const float* __restrict__ g,
                                              const float* __restrict__ be,
                                              const ushort* __restrict__ Bp2,
                                              const float* __restrict__ asrc,
                                              const float* __restrict__ adst,
                                              uint* __restrict__ hW8,
                                              float* __restrict__ esrc,
                                              float* __restrict__ edst) {
    __shared__ ushort hbf[2][16 * PADH];
    int t = threadIdx.x, w = t >> 6, l = t & 63;
    int m = l & 15, q = l >> 4;
    int n0w = blockIdx.x * 32 + w * 16;
    bool active = (n0w < NN);
    int nb = active ? n0w : 0;

    const float4* h4g = reinterpret_cast<const float4*>(hin) + (size_t)nb * 32;
    const float4* g4  = reinterpret_cast<const float4*>(g);
    const float4* be4 = reinterpret_cast<const float4*>(be);
    #pragma unroll
    for (int i = 0; i < 8; ++i) {
        int f4 = l + 64 * i;
        int node = f4 >> 5, c4 = f4 & 31;
        float4 v = h4g[f4];
        float s1 = v.x + v.y + v.z + v.w;
        float s2 = fmaf(v.x, v.x, fmaf(v.y, v.y, fmaf(v.z, v.z, v.w * v.w)));
        #pragma unroll
        for (int mk = 1; mk < 32; mk <<= 1) {
            s1 += __shfl_xor(s1, mk, 64);
            s2 += __shfl_xor(s2, mk, 64);
        }
        float mu = s1 * (1.f / 128.f);
        float var = s2 * (1.f / 128.f) - mu * mu;
        float rs = rsqrtf(var + 1e-5f);
        float4 gg = g4[c4], bb = be4[c4];
        ushort4 pk;
        pk.x = f2b(gelu_f((v.x - mu) * rs * gg.x + bb.x));
        pk.y = f2b(gelu_f((v.y - mu) * rs * gg.y + bb.y));
        pk.z = f2b(gelu_f((v.z - mu) * rs * gg.z + bb.z));
        pk.w = f2b(gelu_f((v.w - mu) * rs * gg.w + bb.w));
        *reinterpret_cast<ushort4*>(&hbf[w][node * PADH + c4 * 4]) = pk;
    }
    __syncthreads();

    const short8* B2 = reinterpret_cast<const short8*>(Bp2);
    floatx4 acc2[8];
    #pragma unroll
    for (int T = 0; T < 8; ++T) acc2[T] = (floatx4){0.f, 0.f, 0.f, 0.f};
    #pragma unroll
    for (int s = 0; s < 4; ++s) {
        short8 a = *reinterpret_cast<const short8*>(&hbf[w][m * PADH + s * 32 + q * 8]);
        #pragma unroll
        for (int T = 0; T < 8; ++T) {
            short8 b = B2[(T * 4 + s) * 64 + l];
            acc2[T] = __builtin_amdgcn_mfma_f32_16x16x32_bf16(a, b, acc2[T], 0, 0, 0);
        }
    }

    __syncthreads();
    #pragma unroll
    for (int j = 0; j < 4; ++j)
        #pragma unroll
        for (int T = 0; T < 8; ++T)
            hbf[w][(q * 4 + j) * PADH + T * 16 + m] = f2b(acc2[T][j]);
    __syncthreads();
    pack_store_fp8(hbf[w], l, n0w, active, hW8);

    float as_[8], ad_[8];
    #pragma unroll
    for (int T = 0; T < 8; ++T) {
        int c = T * 16 + m;
        as_[T] = asrc[c]; ad_[T] = adst[c];
    }
    #pragma unroll
    for (int j = 0; j < 4; ++j) {
        #pragma unroll
        for (int h = 0; h < 4; ++h) {
            float v1 = fmaf(acc2[2 * h][j], as_[2 * h], acc2[2 * h + 1][j] * as_[2 * h + 1]);
            float v2 = fmaf(acc2[2 * h][j], ad_[2 * h], acc2[2 * h + 1][j] * ad_[2 * h + 1]);
            #pragma unroll
            for (int mk = 1; mk < 16; mk <<= 1) {
                v1 += __shfl_xor(v1, mk, 64);
                v2 += __shfl_xor(v2, mk, 64);
            }
            if (m == 0 && active) {
                esrc[(n0w + q * 4 + j) * 4 + h] = v1;
                edst[(n0w + q * 4 + j) * 4 + h] = v2;
            }
        }
    }
}

// ------- edge-parallel attention weights -------

__global__ __launch_bounds__(256) void k_edgew(const int* __restrict__ csr,
                                               const int* __restrict__ dstid,
                                               const float* __restrict__ esrc,
                                               const float* __restrict__ edst,
                                               ushort* __restrict__ wexp) {
    int i = blockIdx.x * 256 + threadIdx.x;
    if (i >= ETOT) return;
    int s = csr[i], d = dstid[i];
    float4 es = reinterpret_cast<const float4*>(esrc)[s];
    float4 ed = reinterpret_cast<const float4*>(edst)[d];
    float e0 = es.x + ed.x, e1 = es.y + ed.y, e2 = es.z + ed.z, e3 = es.w + ed.w;
    e0 = __expf(fmaxf(e0, 0.2f * e0));
    e1 = __expf(fmaxf(e1, 0.2f * e1));
    e2 = __expf(fmaxf(e2, 0.2f * e2));
    e3 = __expf(fmaxf(e3, 0.2f * e3));
    ushort4 pk = { f2b(e0), f2b(e1), f2b(e2), f2b(e3) };
    reinterpret_cast<ushort4*>(wexp)[i] = pk;
}

// ------- GAT aggregate v7: R9 pipeline + pk_fma accumulate + clamp-free (padded) -------

__global__ __launch_bounds__(128) void k_gat(const uint* __restrict__ hW8,
                                             const ushort* __restrict__ wexp,
                                             const int* __restrict__ off,
                                             const int* __restrict__ csr,
                                             const float* __restrict__ bg,
                                             float* __restrict__ out) {
    __shared__ float redA[16][8];
    __shared__ float redD[16];
    int n = blockIdx.x, t = threadIdx.x;
    int wv = t >> 6, l = t & 63;
    int slot = l >> 4;
    int q    = l & 15;
    int hq   = q >> 2;
    int o0 = off[n], o1 = off[n + 1];
    const uint2* hw2 = reinterpret_cast<const uint2*>(hW8);
    floatx2 a01 = {0.f, 0.f}, a23 = {0.f, 0.f}, a45 = {0.f, 0.f}, a67 = {0.f, 0.f};
    float dsum = 0.f;
    int nIter = (o1 - o0 + 15) >> 4;
    int e = o0 + wv * 4 + slot;

    // prologue (csr/wexp padded past ETOT: no clamps anywhere)
    int    srcA = csr[e];      ushort ubA = wexp[e * 4 + hq];
    int    srcB = csr[e + 8];  ushort ubB = wexp[(e + 8) * 4 + hq];
    int    srcC = csr[e + 16]; ushort ubC = wexp[(e + 16) * 4 + hq];
    int    srcD = csr[e + 24]; ushort ubD = wexp[(e + 24) * 4 + hq];
    uint2  rA = hw2[(size_t)srcA * 16 + q];
    uint2  rB = hw2[(size_t)srcB * 16 + q];

    for (int it = 0; it < nIter; ++it) {
        uint2 rC = hw2[(size_t)srcC * 16 + q];
        uint2 rD = hw2[(size_t)srcD * 16 + q];
        int    srcE = csr[e + 32]; ushort ubE = wexp[(e + 32) * 4 + hq];
        int    srcF = csr[e + 40]; ushort ubF = wexp[(e + 40) * 4 + hq];
        float wa = (e     < o1) ? __uint_as_float(((unsigned)ubA) << 16) : 0.f;
        float wb = (e + 8 < o1) ? __uint_as_float(((unsigned)ubB) << 16) : 0.f;
        floatx2 wa2 = {wa, wa}, wb2 = {wb, wb};
        a01 += wa2 * __builtin_amdgcn_cvt_pk_f32_fp8(rA.x, false);
        a23 += wa2 * __builtin_amdgcn_cvt_pk_f32_fp8(rA.x, true);
        a45 += wa2 * __builtin_amdgcn_cvt_pk_f32_fp8(rA.y, false);
        a67 += wa2 * __builtin_amdgcn_cvt_pk_f32_fp8(rA.y, true);
        a01 += wb2 * __builtin_amdgcn_cvt_pk_f32_fp8(rB.x, false);
        a23 += wb2 * __builtin_amdgcn_cvt_pk_f32_fp8(rB.x, true);
        a45 += wb2 * __builtin_amdgcn_cvt_pk_f32_fp8(rB.y, false);
        a67 += wb2 * __builtin_amdgcn_cvt_pk_f32_fp8(rB.y, true);
        dsum += wa + wb;
        e += 16;
        rA = rC; rB = rD;
        srcC = srcE; srcD = srcF;
        ubA = ubC; ubB = ubD; ubC = ubE; ubD = ubF;
    }
    float acc[8] = {a01[0], a01[1], a23[0], a23[1], a45[0], a45[1], a67[0], a67[1]};
    #pragma unroll
    for (int mk = 16; mk <= 32; mk <<= 1) {
        #pragma unroll
        for (int j = 0; j < 8; ++j) acc[j] += __shfl_xor(acc[j], mk, 64);
        dsum += __shfl_xor(dsum, mk, 64);
    }
    if (wv == 1 && l < 16) {
        #pragma unroll
        for (int j = 0; j < 8; ++j) redA[l][j] = acc[j];
        redD[l] = dsum;
    }
    __syncthreads();
    if (wv == 0 && l < 16) {
        float inv = 1.0f / (dsum + redD[l]);
        float4 r0, r1;
        r0.x = (acc[0] + redA[l][0]) * inv + bg[l * 8 + 0];
        r0.y = (acc[1] + redA[l][1]) * inv + bg[l * 8 + 1];
        r0.z = (acc[2] + redA[l][2]) * inv + bg[l * 8 + 2];
        r0.w = (acc[3] + redA[l][3]) * inv + bg[l * 8 + 3];
        r1.x = (acc[4] + redA[l][4]) * inv + bg[l * 8 + 4];
        r1.y = (acc[5] + redA[l][5]) * inv + bg[l * 8 + 5];
        r1.z = (acc[6] + redA[l][6]) * inv + bg[l * 8 + 6];
        r1.w = (acc[7] + redA[l][7]) * inv + bg[l * 8 + 7];
        float4* op = reinterpret_cast<float4*>(out + (size_t)n * HID + l * 8);
        op[0] = r0; op[1] = r1;
    }
}

// ---------------- output linear: fp32 register-tiled 4 nodes x 4 cols ----------------

__global__ __launch_bounds__(64) void k_out(const float* __restrict__ h,
                                            const float* __restrict__ w,
                                            const float* __restrict__ b,
                                            float* __restrict__ out) {
    __shared__ __align__(16) float hr[16 * 132];
    int t = threadIdx.x, n0 = blockIdx.x * 16;
    const float4* h4g = reinterpret_cast<const float4*>(h) + (size_t)n0 * 32;
    float4* hr4 = reinterpret_cast<float4*>(hr);
    #pragma unroll
    for (int i = 0; i < 8; ++i) {
        int f4 = t + 64 * i;
        hr4[(f4 >> 5) * 33 + (f4 & 31)] = h4g[f4];
    }
    __syncthreads();
    int cg = t & 15, ng = t >> 4;
    const float4* w4 = reinterpret_cast<const float4*>(w);
    float4 bb = reinterpret_cast<const float4*>(b)[cg];
    float4 acc[4] = {bb, bb, bb, bb};
    for (int k4 = 0; k4 < 32; ++k4) {
        float4 w0 = w4[(k4 * 4 + 0) * 16 + cg];
        float4 w1 = w4[(k4 * 4 + 1) * 16 + cg];
        float4 w2 = w4[(k4 * 4 + 2) * 16 + cg];
        float4 w3 = w4[(k4 * 4 + 3) * 16 + cg];
        #pragma unroll
        for (int r = 0; r < 4; ++r) {
            float4 hv = hr4[(ng * 4 + r) * 33 + k4];
            acc[r].x = fmaf(hv.x, w0.x, fmaf(hv.y, w1.x, fmaf(hv.z, w2.x, fmaf(hv.w, w3.x, acc[r].x))));
            acc[r].y = fmaf(hv.x, w0.y, fmaf(hv.y, w1.y, fmaf(hv.z, w2.y, fmaf(hv.w, w3.y, acc[r].y))));
            acc[r].z = fmaf(hv.x, w0.z, fmaf(hv.y, w1.z, fmaf(hv.z, w2.z, fmaf(hv.w, w3.z, acc[r].z))));
            acc[r].w = fmaf(hv.x, w0.w, fmaf(hv.y, w1.w, fmaf(hv.z, w2.w, fmaf(hv.w, w3.w, acc[r].w))));
        }
    }
    float4* o4 = reinterpret_cast<float4*>(out) + (size_t)n0 * 16;
    #pragma unroll
    for (int r = 0; r < 4; ++r) o4[(ng * 4 + r) * 16 + cg] = acc[r];
}

extern "C" void kernel_launch(void* const* d_in, const int* in_sizes, int n_in,
                              void* d_out, int out_size, void* d_ws, size_t ws_size,
                              hipStream_t stream) {
    const float* x    = (const float*)d_in[0];
    const int*   ei   = (const int*)  d_in[1];
    const float* w_in = (const float*)d_in[2];
    const float* b_in = (const float*)d_in[3];
    const float* g1   = (const float*)d_in[4];
    const float* be1  = (const float*)d_in[5];
    const float* W1   = (const float*)d_in[6];
    const float* as1  = (const float*)d_in[7];
    const float* ad1  = (const float*)d_in[8];
    const float* bg1  = (const float*)d_in[9];
    const float* g2   = (const float*)d_in[10];
    const float* be2  = (const float*)d_in[11];
    const float* W2   = (const float*)d_in[12];
    const float* as2  = (const float*)d_in[13];
    const float* ad2  = (const float*)d_in[14];
    const float* bg2  = (const float*)d_in[15];
    const float* w_o  = (const float*)d_in[16];
    const float* b_o  = (const float*)d_in[17];
    float* out = (float*)d_out;

    char* p = (char*)d_ws;
    auto take = [&](size_t bytes) {
        void* r = p;
        p += (bytes + 255) & ~(size_t)255;
        return r;
    };
    float*  gout  = (float*)take((size_t)NN * HID * 4);
    float*  h2    = (float*)take((size_t)NN * HID * 4);
    uint*   hW8   = (uint*)take((size_t)NN * HID);       // fp8 gather table
    float*  esrc  = (float*)take((size_t)NN * 4 * 4);
    float*  edst  = (float*)take((size_t)NN * 4 * 4);
    int*    off   = (int*)take((size_t)(NN + 1) * 4);
    int*    csr   = (int*)take((size_t)(ETOT + 64) * 4); // +64 pad (zeroed)
    int*    dstid = (int*)take((size_t)ETOT * 4);
    size_t ovl = (size_t)ETOT * 8 + 512;                 // wexp + pad overread room
    size_t tsz = (size_t)NBK * CAP * 4;
    ushort* wexp  = (ushort*)take(ovl > tsz ? ovl : tsz);
    int*    tmp   = (int*)wexp;
    int*    bcur  = (int*)take((size_t)NBK * 4);
    int*    bstart= (int*)take((size_t)NBK * 4);
    ushort* Bp1   = (ushort*)take((size_t)1024 * 16);
    ushort* BpW1  = (ushort*)take((size_t)2048 * 16);
    ushort* BpW2  = (ushort*)take((size_t)2048 * 16);

    k_packall   <<<20, 256, 0, stream>>>(w_in, W1, W2, Bp1, BpW1, BpW2, bcur);
    k_bucket    <<<BBLK, 1024, 0, stream>>>(ei, bcur, tmp);
    k_bscan     <<<1, NBK, 0, stream>>>(bcur, bstart, off, csr);
    k_bucket2csr<<<NBK, 256, 0, stream>>>(tmp, bcur, bstart, off, csr, dstid);

    int gfeat = (NN + 31) / 32;
    k_infeat<<<gfeat, 128, 0, stream>>>(x, Bp1, b_in, g1, be1, BpW1, as1, ad1, hW8, esrc, edst);
    k_edgew <<<(ETOT + 255) / 256, 256, 0, stream>>>(csr, dstid, esrc, edst, wexp);
    k_gat   <<<NN, 128, 0, stream>>>(hW8, wexp, off, csr, bg1, gout);
    k_feat  <<<gfeat, 128, 0, stream>>>(gout, g2, be2, BpW2, as2, ad2, hW8, esrc, edst);
    k_edgew <<<(ETOT + 255) / 256, 256, 0, stream>>>(csr, dstid, esrc, edst, wexp);
    k_gat   <<<NN, 128, 0, stream>>>(hW8, wexp, off, csr, bg2, h2);
    k_out   <<<NN / 16, 64, 0, stream>>>(h2, w_o, b_o, out);
}

// Round 11
// 282.351 us; speedup vs baseline: 1.5705x; 1.0781x over previous
//
#include <hip/hip_runtime.h>
#include <hip/hip_bf16.h>
#include <math.h>

#define NN   50000
#define EE   1600000
#define ETOT (EE + NN)
#define HID  128
#define INF_ 64
#define OUTF 64

// bucketed CSR build (256 coarse buckets -> coalesced 100B runs)
#define NBK  256    // buckets (contiguous dst ranges)
#define NPB  196    // nodes per bucket (256*196 = 50176 >= NN)
#define CAP  8192   // per-bucket capacity; mean ~6446, sigma ~80
#define BBLK 256    // blocks for k_bucket
#define CHUNK ((ETOT + BBLK - 1) / BBLK)   // 6446 edges per block

#define PADX 72     // xbf row stride (ushorts)
#define PADH 136    // hbf row stride (ushorts)

typedef short  short8  __attribute__((ext_vector_type(8)));
typedef float  floatx4 __attribute__((ext_vector_type(4)));
typedef float  floatx2 __attribute__((ext_vector_type(2)));

__device__ __forceinline__ ushort f2b(float f) {
    __hip_bfloat16 h = __float2bfloat16(f);
    return *reinterpret_cast<ushort*>(&h);
}

__device__ __forceinline__ float gelu_f(float x) {
    float x2 = x * x;
    float u  = 0.7978845608f * fmaf(0.044715f * x2, x, x);
    u = fminf(u, 40.f);
    float t = __expf(2.f * u);
    return x * t / (t + 1.f);
}

// ---------------- CSR build ----------------
// pack: (b<<24) | (src<<8) | dloc   (src<65536 fits 16b, dloc<196 fits 8b)

__global__ __launch_bounds__(1024) void k_bucket(const int* __restrict__ ei,
                                                 int* bcur, int* __restrict__ tmp) {
    __shared__ unsigned sortedv[CHUNK];
    __shared__ int hist[NBK], gbase[NBK], loff[NBK], lcur[NBK];
    int t = threadIdx.x;
    int lo = blockIdx.x * CHUNK;
    int hi = min(lo + CHUNK, ETOT);
    int bsize = hi - lo;
    if (t < NBK) hist[t] = 0;
    __syncthreads();
    for (int i = lo + t; i < hi; i += 1024) {
        int d = (i < EE) ? ei[EE + i] : i - EE;
        atomicAdd(&hist[d / NPB], 1);
    }
    __syncthreads();
    if (t < NBK) {
        int c = hist[t];
        gbase[t] = (c > 0) ? atomicAdd(&bcur[t], c) : 0;
        loff[t] = c;
    }
    __syncthreads();
    for (int d = 1; d < NBK; d <<= 1) {
        int v = (t >= d && t < NBK) ? loff[t - d] : 0;
        __syncthreads();
        if (t < NBK) loff[t] += v;
        __syncthreads();
    }
    if (t < NBK) {
        int ex = loff[t] - hist[t];       // exclusive
        loff[t] = ex;
        lcur[t] = ex;
    }
    __syncthreads();
    for (int i = lo + t; i < hi; i += 1024) {
        unsigned s, d;
        if (i < EE) { s = (unsigned)ei[i]; d = (unsigned)ei[EE + i]; }
        else        { s = d = (unsigned)(i - EE); }
        unsigned b = d / NPB;
        int p = atomicAdd(&lcur[b], 1);
        sortedv[p] = (b << 24) | (s << 8) | (d - b * NPB);
    }
    __syncthreads();
    for (int i = t; i < bsize; i += 1024) {
        unsigned v = sortedv[i];
        unsigned b = v >> 24;
        int pp = gbase[b] + i - loff[b];   // rank within this block's bucket run
        if (pp < CAP) tmp[b * CAP + pp] = (int)(v & 0xFFFFFFu);
    }
}

// scan of 256 bucket sizes; zero csr pad (k_gat reads past o1 unclamped)
__global__ __launch_bounds__(256) void k_bscan(const int* __restrict__ bcur,
                                               int* __restrict__ bstart,
                                               int* __restrict__ off,
                                               int* __restrict__ csr) {
    __shared__ int s[NBK];
    int t = threadIdx.x;
    int v0 = bcur[t];
    s[t] = v0;
    __syncthreads();
    for (int d = 1; d < NBK; d <<= 1) {
        int v = (t >= d) ? s[t - d] : 0;
        __syncthreads();
        s[t] += v;
        __syncthreads();
    }
    bstart[t] = s[t] - v0;
    if (t == 0) off[NN] = ETOT;
    if (t < 64) csr[ETOT + t] = 0;
}

__global__ __launch_bounds__(512) void k_bucket2csr(const int* __restrict__ tmp,
                                                    const int* __restrict__ bcur,
                                                    const int* __restrict__ bstart,
                                                    int* __restrict__ off,
                                                    int* __restrict__ csr) {
    __shared__ int sE[CAP];
    __shared__ int lcnt[NPB];
    __shared__ int loff[NPB];
    int b = blockIdx.x, t = threadIdx.x;
    int n0    = b * NPB;
    int bsize = min(bcur[b], CAP);
    int base  = bstart[b];
    if (t < NPB) lcnt[t] = 0;
    for (int i = t; i < bsize; i += 512) sE[i] = tmp[b * CAP + i];
    __syncthreads();
    for (int i = t; i < bsize; i += 512) atomicAdd(&lcnt[sE[i] & 255], 1);
    __syncthreads();
    if (t < NPB) loff[t] = lcnt[t];
    __syncthreads();
    for (int d = 1; d < NPB; d <<= 1) {      // inclusive scan over 196 bins
        int v = (t >= d && t < NPB) ? loff[t - d] : 0;
        __syncthreads();
        if (t < NPB) loff[t] += v;
        __syncthreads();
    }
    if (t < NPB) {
        int ex = loff[t] - lcnt[t];          // exclusive
        if (n0 + t < NN) off[n0 + t] = base + ex;
        lcnt[t] = ex;                        // cursor
    }
    __syncthreads();
    for (int i = t; i < bsize; i += 512) {
        int v   = sE[i];
        int pos = base + atomicAdd(&lcnt[v & 255], 1);
        csr[pos] = v >> 8;
    }
}

// ---- combined weight packing (w_in, W1, W2) + bcur zeroing: one launch ----

__global__ void k_packall(const float* __restrict__ w_in, const float* __restrict__ W1,
                          const float* __restrict__ W2, ushort* __restrict__ Bp1,
                          ushort* __restrict__ BpW1, ushort* __restrict__ BpW2,
                          int* __restrict__ bcur) {
    int tid = blockIdx.x * 256 + threadIdx.x;
    if (tid < NBK) bcur[tid] = 0;
    const float* W; ushort* dst; int K, id;
    if (tid < 1024)      { W = w_in; dst = Bp1;  K = 64;  id = tid; }
    else if (tid < 3072) { W = W1;   dst = BpW1; K = 128; id = tid - 1024; }
    else if (tid < 5120) { W = W2;   dst = BpW2; K = 128; id = tid - 3072; }
    else return;
    int kst = K >> 5;
    int l = id & 63;
    int s = (id >> 6) % kst;
    int T = id / (kst * 64);
    int m = l & 15, q = l >> 4;
    ushort o[8];
    #pragma unroll
    for (int j = 0; j < 8; ++j)
        o[j] = f2b(W[(s * 32 + q * 8 + j) * 128 + T * 16 + m]);
    uint4 pk;
    pk.x = (unsigned)o[0] | ((unsigned)o[1] << 16);
    pk.y = (unsigned)o[2] | ((unsigned)o[3] << 16);
    pk.z = (unsigned)o[4] | ((unsigned)o[5] << 16);
    pk.w = (unsigned)o[6] | ((unsigned)o[7] << 16);
    reinterpret_cast<uint4*>(dst)[id] = pk;
}

// ---- shared epilogue: stage acc2 (bf16) in LDS, pack fp8 rows, store ----

__device__ __forceinline__ void pack_store_fp8(ushort* hbfw, int l, int n0w, bool active,
                                               uint* __restrict__ hW8) {
    if (!active) return;
    int row = l >> 2, ch = l & 3;
    uint ov[8];
    #pragma unroll
    for (int u = 0; u < 8; ++u) {
        int c0 = ch * 32 + u * 4;
        float f0 = __uint_as_float((uint)hbfw[row * PADH + c0 + 0] << 16);
        float f1 = __uint_as_float((uint)hbfw[row * PADH + c0 + 1] << 16);
        float f2 = __uint_as_float((uint)hbfw[row * PADH + c0 + 2] << 16);
        float f3 = __uint_as_float((uint)hbfw[row * PADH + c0 + 3] << 16);
        int pk = __builtin_amdgcn_cvt_pk_fp8_f32(f0, f1, 0, false);
        pk     = __builtin_amdgcn_cvt_pk_fp8_f32(f2, f3, pk, true);
        ov[u] = (uint)pk;
    }
    uint4* dst = reinterpret_cast<uint4*>(hW8 + (size_t)(n0w + row) * 32 + ch * 8);
    dst[0] = make_uint4(ov[0], ov[1], ov[2], ov[3]);
    dst[1] = make_uint4(ov[4], ov[5], ov[6], ov[7]);
}

// ------- MFMA fused: x@w_in -> +bias -> LN -> GELU -> @W -> fp8 rows + scores -------

__global__ __launch_bounds__(128) void k_infeat(const float* __restrict__ x,
                                                const ushort* __restrict__ Bp1,
                                                const float* __restrict__ bin,
                                                const float* __restrict__ g,
                                                const float* __restrict__ be,
                                                const ushort* __restrict__ Bp2,
                                                const float* __restrict__ asrc,
                                                const float* __restrict__ adst,
                                                uint* __restrict__ hW8,
                                                float* __restrict__ esrc,
                                                float* __restrict__ edst) {
    __shared__ ushort xbf[2][16 * PADX];
    __shared__ ushort hbf[2][16 * PADH];
    int t = threadIdx.x, w = t >> 6, l = t & 63;
    int m = l & 15, q = l >> 4;
    int n0w = blockIdx.x * 32 + w * 16;
    bool active = (n0w < NN);
    int nb = active ? n0w : 0;

    const float4* x4 = reinterpret_cast<const float4*>(x) + (size_t)nb * 16;
    #pragma unroll
    for (int i = 0; i < 4; ++i) {
        int f4 = l + 64 * i;
        int node = f4 >> 4, c4 = f4 & 15;
        float4 v = x4[f4];
        ushort4 pk = { f2b(v.x), f2b(v.y), f2b(v.z), f2b(v.w) };
        *reinterpret_cast<ushort4*>(&xbf[w][node * PADX + c4 * 4]) = pk;
    }
    __syncthreads();

    const short8* B1 = reinterpret_cast<const short8*>(Bp1);
    floatx4 acc1[8];
    #pragma unroll
    for (int T = 0; T < 8; ++T) acc1[T] = (floatx4){0.f, 0.f, 0.f, 0.f};
    #pragma unroll
    for (int s = 0; s < 2; ++s) {
        short8 a = *reinterpret_cast<const short8*>(&xbf[w][m * PADX + s * 32 + q * 8]);
        #pragma unroll
        for (int T = 0; T < 8; ++T) {
            short8 b = B1[(T * 2 + s) * 64 + l];
            acc1[T] = __builtin_amdgcn_mfma_f32_16x16x32_bf16(a, b, acc1[T], 0, 0, 0);
        }
    }

    float bc[8], gc[8], bec[8];
    #pragma unroll
    for (int T = 0; T < 8; ++T) {
        int c = T * 16 + m;
        bc[T] = bin[c]; gc[T] = g[c]; bec[T] = be[c];
    }
    #pragma unroll
    for (int j = 0; j < 4; ++j) {
        float s1 = 0.f, s2 = 0.f;
        #pragma unroll
        for (int T = 0; T < 8; ++T) {
            float v = acc1[T][j] + bc[T];
            s1 += v; s2 = fmaf(v, v, s2);
        }
        #pragma unroll
        for (int mk = 1; mk < 16; mk <<= 1) {
            s1 += __shfl_xor(s1, mk, 64);
            s2 += __shfl_xor(s2, mk, 64);
        }
        float mu = s1 * (1.f / 128.f);
        float var = s2 * (1.f / 128.f) - mu * mu;
        float rs = rsqrtf(var + 1e-5f);
        #pragma unroll
        for (int T = 0; T < 8; ++T) {
            float v = acc1[T][j] + bc[T];
            float y = (v - mu) * rs * gc[T] + bec[T];
            hbf[w][(q * 4 + j) * PADH + T * 16 + m] = f2b(gelu_f(y));
        }
    }
    __syncthreads();

    const short8* B2 = reinterpret_cast<const short8*>(Bp2);
    floatx4 acc2[8];
    #pragma unroll
    for (int T = 0; T < 8; ++T) acc2[T] = (floatx4){0.f, 0.f, 0.f, 0.f};
    #pragma unroll
    for (int s = 0; s < 4; ++s) {
        short8 a = *reinterpret_cast<const short8*>(&hbf[w][m * PADH + s * 32 + q * 8]);
        #pragma unroll
        for (int T = 0; T < 8; ++T) {
            short8 b = B2[(T * 4 + s) * 64 + l];
            acc2[T] = __builtin_amdgcn_mfma_f32_16x16x32_bf16(a, b, acc2[T], 0, 0, 0);
        }
    }

    __syncthreads();
    #pragma unroll
    for (int j = 0; j < 4; ++j)
        #pragma unroll
        for (int T = 0; T < 8; ++T)
            hbf[w][(q * 4 + j) * PADH + T * 16 + m] = f2b(acc2[T][j]);
    __syncthreads();
    pack_store_fp8(hbf[w], l, n0w, active, hW8);

    float as_[8], ad_[8];
    #pragma unroll
    for (int T = 0; T < 8; ++T) {
        int c = T * 16 + m;
        as_[T] = asrc[c]; ad_[T] = adst[c];
    }
    #pragma unroll
    for (int j = 0; j < 4; ++j) {
        #pragma unroll
        for (int h = 0; h < 4; ++h) {
            float v1 = fmaf(acc2[2 * h][j], as_[2 * h], acc2[2 * h + 1][j] * as_[2 * h + 1]);
            float v2 = fmaf(acc2[2 * h][j], ad_[2 * h], acc2[2 * h + 1][j] * ad_[2 * h + 1]);
            #pragma unroll
            for (int mk = 1; mk < 16; mk <<= 1) {
                v1 += __shfl_xor(v1, mk, 64);
                v2 += __shfl_xor(v2, mk, 64);
            }
            if (m == 0 && active) {
                esrc[(n0w + q * 4 + j) * 4 + h] = v1;
                edst[(n0w + q * 4 + j) * 4 + h] = v2;
            }
        }
    }
}

// ------- MFMA fused layer-2: LN(gout) -> GELU -> @W2 -> fp8 rows + scores -------

__global__ __launch_bounds__(128) void k_feat(const float* __restrict__ hin,
                                              const float* __restrict__ g,
                                              const float* __restrict__ be,
                                              const ushort* __restrict__ Bp2,
                                              const float* __restrict__ asrc,
                                              const float* __restrict__ adst,
                                              uint* __restrict__ hW8,
                                              float* __restrict__ esrc,
                                              float* __restrict__ edst) {
    __shared__ ushort hbf[2][16 * PADH];
    int t = threadIdx.x, w = t >> 6, l = t & 63;
    int m = l & 15, q = l >> 4;
    int n0w = blockIdx.x * 32 + w * 16;
    bool active = (n0w < NN);
    int nb = active ? n0w : 0;

    const float4* h4g = reinterpret_cast<const float4*>(hin) + (size_t)nb * 32;
    const float4* g4  = reinterpret_cast<const float4*>(g);
    const float4* be4 = reinterpret_cast<const float4*>(be);
    #pragma unroll
    for (int i = 0; i < 8; ++i) {
        int f4 = l + 64 * i;
        int node = f4 >> 5, c4 = f4 & 31;
        float4 v = h4g[f4];
        float s1 = v.x + v.y + v.z + v.w;
        float s2 = fmaf(v.x, v.x, fmaf(v.y, v.y, fmaf(v.z, v.z, v.w * v.w)));
        #pragma unroll
        for (int mk = 1; mk < 32; mk <<= 1) {
            s1 += __shfl_xor(s1, mk, 64);
            s2 += __shfl_xor(s2, mk, 64);
        }
        float mu = s1 * (1.f / 128.f);
        float var = s2 * (1.f / 128.f) - mu * mu;
        float rs = rsqrtf(var + 1e-5f);
        float4 gg = g4[c4], bb = be4[c4];
        ushort4 pk;
        pk.x = f2b(gelu_f((v.x - mu) * rs * gg.x + bb.x));
        pk.y = f2b(gelu_f((v.y - mu) * rs * gg.y + bb.y));
        pk.z = f2b(gelu_f((v.z - mu) * rs * gg.z + bb.z));
        pk.w = f2b(gelu_f((v.w - mu) * rs * gg.w + bb.w));
        *reinterpret_cast<ushort4*>(&hbf[w][node * PADH + c4 * 4]) = pk;
    }
    __syncthreads();

    const short8* B2 = reinterpret_cast<const short8*>(Bp2);
    floatx4 acc2[8];
    #pragma unroll
    for (int T = 0; T < 8; ++T) acc2[T] = (floatx4){0.f, 0.f, 0.f, 0.f};
    #pragma unroll
    for (int s = 0; s < 4; ++s) {
        short8 a = *reinterpret_cast<const short8*>(&hbf[w][m * PADH + s * 32 + q * 8]);
        #pragma unroll
        for (int T = 0; T < 8; ++T) {
            short8 b = B2[(T * 4 + s) * 64 + l];
            acc2[T] = __builtin_amdgcn_mfma_f32_16x16x32_bf16(a, b, acc2[T], 0, 0, 0);
        }
    }

    __syncthreads();
    #pragma unroll
    for (int j = 0; j < 4; ++j)
        #pragma unroll
        for (int T = 0; T < 8; ++T)
            hbf[w][(q * 4 + j) * PADH + T * 16 + m] = f2b(acc2[T][j]);
    __syncthreads();
    pack_store_fp8(hbf[w], l, n0w, active, hW8);

    float as_[8], ad_[8];
    #pragma unroll
    for (int T = 0; T < 8; ++T) {
        int c = T * 16 + m;
        as_[T] = asrc[c]; ad_[T] = adst[c];
    }
    #pragma unroll
    for (int j = 0; j < 4; ++j) {
        #pragma unroll
        for (int h = 0; h < 4; ++h) {
            float v1 = fmaf(acc2[2 * h][j], as_[2 * h], acc2[2 * h + 1][j] * as_[2 * h + 1]);
            float v2 = fmaf(acc2[2 * h][j], ad_[2 * h], acc2[2 * h + 1][j] * ad_[2 * h + 1]);
            #pragma unroll
            for (int mk = 1; mk < 16; mk <<= 1) {
                v1 += __shfl_xor(v1, mk, 64);
                v2 += __shfl_xor(v2, mk, 64);
            }
            if (m == 0 && active) {
                esrc[(n0w + q * 4 + j) * 4 + h] = v1;
                edst[(n0w + q * 4 + j) * 4 + h] = v2;
            }
        }
    }
}

// ------- GAT aggregate v8: fused in-loop scores (k_edgew deleted) -------
// 128 thr = 2 waves x 4 edge-slots x 16 lane-groups (uint2 = 8 fp8 cols).
// w = exp(lrelu(esrc[src*4+hq] + edst[n*4+hq])) computed in-pipeline:
// es load issues alongside row load (both depend on src loaded one body back).

__global__ __launch_bounds__(128) void k_gat(const uint* __restrict__ hW8,
                                             const float* __restrict__ esrc,
                                             const float* __restrict__ edst,
                                             const int* __restrict__ off,
                                             const int* __restrict__ csr,
                                             const float* __restrict__ bg,
                                             float* __restrict__ out) {
    __shared__ float redA[16][8];
    __shared__ float redD[16];
    int n = blockIdx.x, t = threadIdx.x;
    int wv = t >> 6, l = t & 63;
    int slot = l >> 4;
    int q    = l & 15;
    int hq   = q >> 2;
    int o0 = off[n], o1 = off[n + 1];
    float ednh = edst[n * 4 + hq];
    const uint2* hw2 = reinterpret_cast<const uint2*>(hW8);
    floatx2 a01 = {0.f, 0.f}, a23 = {0.f, 0.f}, a45 = {0.f, 0.f}, a67 = {0.f, 0.f};
    float dsum = 0.f;
    int nIter = (o1 - o0 + 15) >> 4;
    int e = o0 + wv * 4 + slot;

    // prologue (csr padded with zeros past ETOT: no clamps)
    int srcA = csr[e];
    int srcB = csr[e + 8];
    int srcC = csr[e + 16];
    int srcD = csr[e + 24];
    float esA = esrc[srcA * 4 + hq];
    float esB = esrc[srcB * 4 + hq];
    uint2 rA = hw2[(size_t)srcA * 16 + q];
    uint2 rB = hw2[(size_t)srcB * 16 + q];

    for (int it = 0; it < nIter; ++it) {
        uint2 rC = hw2[(size_t)srcC * 16 + q];
        uint2 rD = hw2[(size_t)srcD * 16 + q];
        float esC = esrc[srcC * 4 + hq];
        float esD = esrc[srcD * 4 + hq];
        int srcE = csr[e + 32];
        int srcF = csr[e + 40];
        float ea = esA + ednh; ea = fmaxf(ea, 0.2f * ea);
        float eb = esB + ednh; eb = fmaxf(eb, 0.2f * eb);
        float wa = (e     < o1) ? __expf(ea) : 0.f;
        float wb = (e + 8 < o1) ? __expf(eb) : 0.f;
        floatx2 wa2 = {wa, wa}, wb2 = {wb, wb};
        a01 += wa2 * __builtin_amdgcn_cvt_pk_f32_fp8(rA.x, false);
        a23 += wa2 * __builtin_amdgcn_cvt_pk_f32_fp8(rA.x, true);
        a45 += wa2 * __builtin_amdgcn_cvt_pk_f32_fp8(rA.y, false);
        a67 += wa2 * __builtin_amdgcn_cvt_pk_f32_fp8(rA.y, true);
        a01 += wb2 * __builtin_amdgcn_cvt_pk_f32_fp8(rB.x, false);
        a23 += wb2 * __builtin_amdgcn_cvt_pk_f32_fp8(rB.x, true);
        a45 += wb2 * __builtin_amdgcn_cvt_pk_f32_fp8(rB.y, false);
        a67 += wb2 * __builtin_amdgcn_cvt_pk_f32_fp8(rB.y, true);
        dsum += wa + wb;
        e += 16;
        rA = rC; rB = rD;
        esA = esC; esB = esD;
        srcC = srcE; srcD = srcF;
    }
    float acc[8] = {a01[0], a01[1], a23[0], a23[1], a45[0], a45[1], a67[0], a67[1]};
    #pragma unroll
    for (int mk = 16; mk <= 32; mk <<= 1) {
        #pragma unroll
        for (int j = 0; j < 8; ++j) acc[j] += __shfl_xor(acc[j], mk, 64);
        dsum += __shfl_xor(dsum, mk, 64);
    }
    if (wv == 1 && l < 16) {
        #pragma unroll
        for (int j = 0; j < 8; ++j) redA[l][j] = acc[j];
        redD[l] = dsum;
    }
    __syncthreads();
    if (wv == 0 && l < 16) {
        float inv = 1.0f / (dsum + redD[l]);
        float4 r0, r1;
        r0.x = (acc[0] + redA[l][0]) * inv + bg[l * 8 + 0];
        r0.y = (acc[1] + redA[l][1]) * inv + bg[l * 8 + 1];
        r0.z = (acc[2] + redA[l][2]) * inv + bg[l * 8 + 2];
        r0.w = (acc[3] + redA[l][3]) * inv + bg[l * 8 + 3];
        r1.x = (acc[4] + redA[l][4]) * inv + bg[l * 8 + 4];
        r1.y = (acc[5] + redA[l][5]) * inv + bg[l * 8 + 5];
        r1.z = (acc[6] + redA[l][6]) * inv + bg[l * 8 + 6];
        r1.w = (acc[7] + redA[l][7]) * inv + bg[l * 8 + 7];
        float4* op = reinterpret_cast<float4*>(out + (size_t)n * HID + l * 8);
        op[0] = r0; op[1] = r1;
    }
}

// ---------------- output linear: 32 nodes/block, 4 nodes x 4 cols per thread ----------------

__global__ __launch_bounds__(128) void k_out(const float* __restrict__ h,
                                             const float* __restrict__ w,
                                             const float* __restrict__ b,
                                             float* __restrict__ out) {
    __shared__ __align__(16) float hr[32 * 132];
    int t = threadIdx.x, n0 = blockIdx.x * 32;
    const float4* h4g = reinterpret_cast<const float4*>(h) + (size_t)n0 * 32;
    float4* hr4 = reinterpret_cast<float4*>(hr);
    #pragma unroll
    for (int i = 0; i < 8; ++i) {
        int f4 = t + 128 * i;          // reads may run past NN into ws scratch: safe
        hr4[(f4 >> 5) * 33 + (f4 & 31)] = h4g[f4];
    }
    __syncthreads();
    int cg = t & 15, ng = t >> 4;      // ng in 0..7 -> nodes ng*4..ng*4+3
    const float4* w4 = reinterpret_cast<const float4*>(w);
    float4 bb = reinterpret_cast<const float4*>(b)[cg];
    float4 acc[4] = {bb, bb, bb, bb};
    for (int k4 = 0; k4 < 32; ++k4) {
        float4 w0 = w4[(k4 * 4 + 0) * 16 + cg];
        float4 w1 = w4[(k4 * 4 + 1) * 16 + cg];
        float4 w2 = w4[(k4 * 4 + 2) * 16 + cg];
        float4 w3 = w4[(k4 * 4 + 3) * 16 + cg];
        #pragma unroll
        for (int r = 0; r < 4; ++r) {
            float4 hv = hr4[(ng * 4 + r) * 33 + k4];
            acc[r].x = fmaf(hv.x, w0.x, fmaf(hv.y, w1.x, fmaf(hv.z, w2.x, fmaf(hv.w, w3.x, acc[r].x))));
            acc[r].y = fmaf(hv.x, w0.y, fmaf(hv.y, w1.y, fmaf(hv.z, w2.y, fmaf(hv.w, w3.y, acc[r].y))));
            acc[r].z = fmaf(hv.x, w0.z, fmaf(hv.y, w1.z, fmaf(hv.z, w2.z, fmaf(hv.w, w3.z, acc[r].z))));
            acc[r].w = fmaf(hv.x, w0.w, fmaf(hv.y, w1.w, fmaf(hv.z, w2.w, fmaf(hv.w, w3.w, acc[r].w))));
        }
    }
    float4* o4 = reinterpret_cast<float4*>(out) + (size_t)n0 * 16;
    #pragma unroll
    for (int r = 0; r < 4; ++r) {
        if (n0 + ng * 4 + r < NN)
            o4[(ng * 4 + r) * 16 + cg] = acc[r];
    }
}

extern "C" void kernel_launch(void* const* d_in, const int* in_sizes, int n_in,
                              void* d_out, int out_size, void* d_ws, size_t ws_size,
                              hipStream_t stream) {
    const float* x    = (const float*)d_in[0];
    const int*   ei   = (const int*)  d_in[1];
    const float* w_in = (const float*)d_in[2];
    const float* b_in = (const float*)d_in[3];
    const float* g1   = (const float*)d_in[4];
    const float* be1  = (const float*)d_in[5];
    const float* W1   = (const float*)d_in[6];
    const float* as1  = (const float*)d_in[7];
    const float* ad1  = (const float*)d_in[8];
    const float* bg1  = (const float*)d_in[9];
    const float* g2   = (const float*)d_in[10];
    const float* be2  = (const float*)d_in[11];
    const float* W2   = (const float*)d_in[12];
    const float* as2  = (const float*)d_in[13];
    const float* ad2  = (const float*)d_in[14];
    const float* bg2  = (const float*)d_in[15];
    const float* w_o  = (const float*)d_in[16];
    const float* b_o  = (const float*)d_in[17];
    float* out = (float*)d_out;

    char* p = (char*)d_ws;
    auto take = [&](size_t bytes) {
        void* r = p;
        p += (bytes + 255) & ~(size_t)255;
        return r;
    };
    float*  gout  = (float*)take((size_t)NN * HID * 4);
    float*  h2    = (float*)take((size_t)NN * HID * 4);
    uint*   hW8   = (uint*)take((size_t)NN * HID);       // fp8 gather table
    float*  esrc  = (float*)take((size_t)NN * 4 * 4);
    float*  edst  = (float*)take((size_t)NN * 4 * 4);
    int*    off   = (int*)take((size_t)(NN + 1) * 4);
    int*    csr   = (int*)take((size_t)(ETOT + 64) * 4); // +64 zeroed pad
    int*    tmp   = (int*)take((size_t)NBK * CAP * 4);   // 8.4 MB bucket staging
    int*    bcur  = (int*)take((size_t)NBK * 4);
    int*    bstart= (int*)take((size_t)NBK * 4);
    ushort* Bp1   = (ushort*)take((size_t)1024 * 16);
    ushort* BpW1  = (ushort*)take((size_t)2048 * 16);
    ushort* BpW2  = (ushort*)take((size_t)2048 * 16);

    k_packall   <<<20, 256, 0, stream>>>(w_in, W1, W2, Bp1, BpW1, BpW2, bcur);
    k_bucket    <<<BBLK, 1024, 0, stream>>>(ei, bcur, tmp);
    k_bscan     <<<1, NBK, 0, stream>>>(bcur, bstart, off, csr);
    k_bucket2csr<<<NBK, 512, 0, stream>>>(tmp, bcur, bstart, off, csr);

    int gfeat = (NN + 31) / 32;
    k_infeat<<<gfeat, 128, 0, stream>>>(x, Bp1, b_in, g1, be1, BpW1, as1, ad1, hW8, esrc, edst);
    k_gat   <<<NN, 128, 0, stream>>>(hW8, esrc, edst, off, csr, bg1, gout);
    k_feat  <<<gfeat, 128, 0, stream>>>(gout, g2, be2, BpW2, as2, ad2, hW8, esrc, edst);
    k_gat   <<<NN, 128, 0, stream>>>(hW8, esrc, edst, off, csr, bg2, h2);
    k_out   <<<(NN + 31) / 32, 128, 0, stream>>>(h2, w_o, b_o, out);
}

// Round 12
// 268.482 us; speedup vs baseline: 1.6516x; 1.0517x over previous
//
#include <hip/hip_runtime.h>
#include <hip/hip_bf16.h>
#include <math.h>

#define NN   50000
#define EE   1600000
#define ETOT (EE + NN)
#define HID  128
#define INF_ 64
#define OUTF 64

// bucketed CSR build (256 coarse buckets -> coalesced ~100B runs)
#define NBK  256    // buckets (contiguous dst ranges)
#define NPB  196    // nodes per bucket (256*196 = 50176 >= NN)
#define CAP  8192   // per-bucket capacity; mean ~6446
#define BBLK 256    // blocks for k_bucket
#define CHUNK ((ETOT + BBLK - 1) / BBLK)   // 6446 edges per block

#define PADX 72     // xbf row stride (ushorts)
#define PADH 136    // hbf row stride (ushorts)

typedef short  short8  __attribute__((ext_vector_type(8)));
typedef float  floatx4 __attribute__((ext_vector_type(4)));
typedef float  floatx2 __attribute__((ext_vector_type(2)));

__device__ __forceinline__ ushort f2b(float f) {
    __hip_bfloat16 h = __float2bfloat16(f);
    return *reinterpret_cast<ushort*>(&h);
}
__device__ __forceinline__ float b2f_lo(uint v) { return __uint_as_float(v << 16); }
__device__ __forceinline__ float b2f_hi(uint v) { return __uint_as_float(v & 0xffff0000u); }

__device__ __forceinline__ float gelu_f(float x) {
    float x2 = x * x;
    float u  = 0.7978845608f * fmaf(0.044715f * x2, x, x);
    u = fminf(u, 40.f);
    float t = __expf(2.f * u);
    return x * t / (t + 1.f);
}

// ---------------- CSR build ----------------
// pack: (b<<24) | (src<<8) | dloc

__global__ __launch_bounds__(1024) void k_bucket(const int* __restrict__ ei,
                                                 int* bcur, int* __restrict__ tmp) {
    __shared__ unsigned sortedv[CHUNK];
    __shared__ int hist[NBK], gbase[NBK], loff[NBK], lcur[NBK];
    int t = threadIdx.x;
    int lo = blockIdx.x * CHUNK;
    int hi = min(lo + CHUNK, ETOT);
    int bsize = hi - lo;
    if (t < NBK) hist[t] = 0;
    __syncthreads();
    for (int i = lo + t; i < hi; i += 1024) {
        int d = (i < EE) ? ei[EE + i] : i - EE;
        atomicAdd(&hist[d / NPB], 1);
    }
    __syncthreads();
    if (t < NBK) {
        int c = hist[t];
        gbase[t] = (c > 0) ? atomicAdd(&bcur[t], c) : 0;
        loff[t] = c;
    }
    __syncthreads();
    for (int d = 1; d < NBK; d <<= 1) {
        int v = (t >= d && t < NBK) ? loff[t - d] : 0;
        __syncthreads();
        if (t < NBK) loff[t] += v;
        __syncthreads();
    }
    if (t < NBK) {
        int ex = loff[t] - hist[t];
        loff[t] = ex;
        lcur[t] = ex;
    }
    __syncthreads();
    for (int i = lo + t; i < hi; i += 1024) {
        unsigned s, d;
        if (i < EE) { s = (unsigned)ei[i]; d = (unsigned)ei[EE + i]; }
        else        { s = d = (unsigned)(i - EE); }
        unsigned b = d / NPB;
        int p = atomicAdd(&lcur[b], 1);
        sortedv[p] = (b << 24) | (s << 8) | (d - b * NPB);
    }
    __syncthreads();
    for (int i = t; i < bsize; i += 1024) {
        unsigned v = sortedv[i];
        unsigned b = v >> 24;
        int pp = gbase[b] + i - loff[b];
        if (pp < CAP) tmp[b * CAP + pp] = (int)(v & 0xFFFFFFu);
    }
}

// one block per bucket; in-block scan of bcur replaces the old k_bscan kernel
__global__ __launch_bounds__(512) void k_bucket2csr(const int* __restrict__ tmp,
                                                    const int* __restrict__ bcur,
                                                    int* __restrict__ off,
                                                    int* __restrict__ csr) {
    __shared__ int sE[CAP];
    __shared__ int lcnt[NPB];
    __shared__ int loff[NPB];
    __shared__ int sb[NBK];
    int b = blockIdx.x, t = threadIdx.x;
    int n0    = b * NPB;
    int bsize = min(bcur[b], CAP);
    // redundant per-block exclusive scan of the 256 bucket sizes -> base
    if (t < NBK) sb[t] = bcur[t];
    __syncthreads();
    for (int d = 1; d < NBK; d <<= 1) {
        int v = (t >= d && t < NBK) ? sb[t - d] : 0;
        __syncthreads();
        if (t < NBK) sb[t] += v;
        __syncthreads();
    }
    int base = sb[b] - bcur[b];
    if (b == 0 && t == 0) off[NN] = ETOT;
    if (t < NPB) lcnt[t] = 0;
    for (int i = t; i < bsize; i += 512) sE[i] = tmp[b * CAP + i];
    __syncthreads();
    for (int i = t; i < bsize; i += 512) atomicAdd(&lcnt[sE[i] & 255], 1);
    __syncthreads();
    if (t < NPB) loff[t] = lcnt[t];
    __syncthreads();
    for (int d = 1; d < NPB; d <<= 1) {
        int v = (t >= d && t < NPB) ? loff[t - d] : 0;
        __syncthreads();
        if (t < NPB) loff[t] += v;
        __syncthreads();
    }
    if (t < NPB) {
        int ex = loff[t] - lcnt[t];
        if (n0 + t < NN) off[n0 + t] = base + ex;
        lcnt[t] = ex;
    }
    __syncthreads();
    for (int i = t; i < bsize; i += 512) {
        int v   = sE[i];
        int pos = base + atomicAdd(&lcnt[v & 255], 1);
        csr[pos] = v >> 8;
    }
}

// ---- combined weight packing + bcur zeroing + csr pad zeroing: one launch ----

__global__ void k_packall(const float* __restrict__ w_in, const float* __restrict__ W1,
                          const float* __restrict__ W2, ushort* __restrict__ Bp1,
                          ushort* __restrict__ BpW1, ushort* __restrict__ BpW2,
                          int* __restrict__ bcur, int* __restrict__ csr) {
    int tid = blockIdx.x * 256 + threadIdx.x;
    if (tid < NBK) bcur[tid] = 0;
    if (tid < 64) csr[ETOT + tid] = 0;   // pad: k_gat reads past o1 unclamped
    const float* W; ushort* dst; int K, id;
    if (tid < 1024)      { W = w_in; dst = Bp1;  K = 64;  id = tid; }
    else if (tid < 3072) { W = W1;   dst = BpW1; K = 128; id = tid - 1024; }
    else if (tid < 5120) { W = W2;   dst = BpW2; K = 128; id = tid - 3072; }
    else return;
    int kst = K >> 5;
    int l = id & 63;
    int s = (id >> 6) % kst;
    int T = id / (kst * 64);
    int m = l & 15, q = l >> 4;
    ushort o[8];
    #pragma unroll
    for (int j = 0; j < 8; ++j)
        o[j] = f2b(W[(s * 32 + q * 8 + j) * 128 + T * 16 + m]);
    uint4 pk;
    pk.x = (unsigned)o[0] | ((unsigned)o[1] << 16);
    pk.y = (unsigned)o[2] | ((unsigned)o[3] << 16);
    pk.z = (unsigned)o[4] | ((unsigned)o[5] << 16);
    pk.w = (unsigned)o[6] | ((unsigned)o[7] << 16);
    reinterpret_cast<uint4*>(dst)[id] = pk;
}

// ---- shared epilogue: stage acc2 (bf16) in LDS, pack fp8 rows, store ----

__device__ __forceinline__ void pack_store_fp8(ushort* hbfw, int l, int n0w, bool active,
                                               uint* __restrict__ hW8) {
    if (!active) return;
    int row = l >> 2, ch = l & 3;
    uint ov[8];
    #pragma unroll
    for (int u = 0; u < 8; ++u) {
        int c0 = ch * 32 + u * 4;
        float f0 = __uint_as_float((uint)hbfw[row * PADH + c0 + 0] << 16);
        float f1 = __uint_as_float((uint)hbfw[row * PADH + c0 + 1] << 16);
        float f2 = __uint_as_float((uint)hbfw[row * PADH + c0 + 2] << 16);
        float f3 = __uint_as_float((uint)hbfw[row * PADH + c0 + 3] << 16);
        int pk = __builtin_amdgcn_cvt_pk_fp8_f32(f0, f1, 0, false);
        pk     = __builtin_amdgcn_cvt_pk_fp8_f32(f2, f3, pk, true);
        ov[u] = (uint)pk;
    }
    uint4* dst = reinterpret_cast<uint4*>(hW8 + (size_t)(n0w + row) * 32 + ch * 8);
    dst[0] = make_uint4(ov[0], ov[1], ov[2], ov[3]);
    dst[1] = make_uint4(ov[4], ov[5], ov[6], ov[7]);
}

// ------- MFMA fused: x@w_in -> +bias -> LN -> GELU -> @W -> fp8 rows + scores -------

__global__ __launch_bounds__(128) void k_infeat(const float* __restrict__ x,
                                                const ushort* __restrict__ Bp1,
                                                const float* __restrict__ bin,
                                                const float* __restrict__ g,
                                                const float* __restrict__ be,
                                                const ushort* __restrict__ Bp2,
                                                const float* __restrict__ asrc,
                                                const float* __restrict__ adst,
                                                uint* __restrict__ hW8,
                                                float* __restrict__ esrc,
                                                float* __restrict__ edst) {
    __shared__ ushort xbf[2][16 * PADX];
    __shared__ ushort hbf[2][16 * PADH];
    int t = threadIdx.x, w = t >> 6, l = t & 63;
    int m = l & 15, q = l >> 4;
    int n0w = blockIdx.x * 32 + w * 16;
    bool active = (n0w < NN);
    int nb = active ? n0w : 0;

    const float4* x4 = reinterpret_cast<const float4*>(x) + (size_t)nb * 16;
    #pragma unroll
    for (int i = 0; i < 4; ++i) {
        int f4 = l + 64 * i;
        int node = f4 >> 4, c4 = f4 & 15;
        float4 v = x4[f4];
        ushort4 pk = { f2b(v.x), f2b(v.y), f2b(v.z), f2b(v.w) };
        *reinterpret_cast<ushort4*>(&xbf[w][node * PADX + c4 * 4]) = pk;
    }
    __syncthreads();

    const short8* B1 = reinterpret_cast<const short8*>(Bp1);
    floatx4 acc1[8];
    #pragma unroll
    for (int T = 0; T < 8; ++T) acc1[T] = (floatx4){0.f, 0.f, 0.f, 0.f};
    #pragma unroll
    for (int s = 0; s < 2; ++s) {
        short8 a = *reinterpret_cast<const short8*>(&xbf[w][m * PADX + s * 32 + q * 8]);
        #pragma unroll
        for (int T = 0; T < 8; ++T) {
            short8 b = B1[(T * 2 + s) * 64 + l];
            acc1[T] = __builtin_amdgcn_mfma_f32_16x16x32_bf16(a, b, acc1[T], 0, 0, 0);
        }
    }

    float bc[8], gc[8], bec[8];
    #pragma unroll
    for (int T = 0; T < 8; ++T) {
        int c = T * 16 + m;
        bc[T] = bin[c]; gc[T] = g[c]; bec[T] = be[c];
    }
    #pragma unroll
    for (int j = 0; j < 4; ++j) {
        float s1 = 0.f, s2 = 0.f;
        #pragma unroll
        for (int T = 0; T < 8; ++T) {
            float v = acc1[T][j] + bc[T];
            s1 += v; s2 = fmaf(v, v, s2);
        }
        #pragma unroll
        for (int mk = 1; mk < 16; mk <<= 1) {
            s1 += __shfl_xor(s1, mk, 64);
            s2 += __shfl_xor(s2, mk, 64);
        }
        float mu = s1 * (1.f / 128.f);
        float var = s2 * (1.f / 128.f) - mu * mu;
        float rs = rsqrtf(var + 1e-5f);
        #pragma unroll
        for (int T = 0; T < 8; ++T) {
            float v = acc1[T][j] + bc[T];
            float y = (v - mu) * rs * gc[T] + bec[T];
            hbf[w][(q * 4 + j) * PADH + T * 16 + m] = f2b(gelu_f(y));
        }
    }
    __syncthreads();

    const short8* B2 = reinterpret_cast<const short8*>(Bp2);
    floatx4 acc2[8];
    #pragma unroll
    for (int T = 0; T < 8; ++T) acc2[T] = (floatx4){0.f, 0.f, 0.f, 0.f};
    #pragma unroll
    for (int s = 0; s < 4; ++s) {
        short8 a = *reinterpret_cast<const short8*>(&hbf[w][m * PADH + s * 32 + q * 8]);
        #pragma unroll
        for (int T = 0; T < 8; ++T) {
            short8 b = B2[(T * 4 + s) * 64 + l];
            acc2[T] = __builtin_amdgcn_mfma_f32_16x16x32_bf16(a, b, acc2[T], 0, 0, 0);
        }
    }

    __syncthreads();
    #pragma unroll
    for (int j = 0; j < 4; ++j)
        #pragma unroll
        for (int T = 0; T < 8; ++T)
            hbf[w][(q * 4 + j) * PADH + T * 16 + m] = f2b(acc2[T][j]);
    __syncthreads();
    pack_store_fp8(hbf[w], l, n0w, active, hW8);

    float as_[8], ad_[8];
    #pragma unroll
    for (int T = 0; T < 8; ++T) {
        int c = T * 16 + m;
        as_[T] = asrc[c]; ad_[T] = adst[c];
    }
    #pragma unroll
    for (int j = 0; j < 4; ++j) {
        #pragma unroll
        for (int h = 0; h < 4; ++h) {
            float v1 = fmaf(acc2[2 * h][j], as_[2 * h], acc2[2 * h + 1][j] * as_[2 * h + 1]);
            float v2 = fmaf(acc2[2 * h][j], ad_[2 * h], acc2[2 * h + 1][j] * ad_[2 * h + 1]);
            #pragma unroll
            for (int mk = 1; mk < 16; mk <<= 1) {
                v1 += __shfl_xor(v1, mk, 64);
                v2 += __shfl_xor(v2, mk, 64);
            }
            if (m == 0 && active) {
                esrc[(n0w + q * 4 + j) * 4 + h] = v1;
                edst[(n0w + q * 4 + j) * 4 + h] = v2;
            }
        }
    }
}

// ------- MFMA fused layer-2 (bf16 input): LN -> GELU -> @W2 -> fp8 rows + scores -------

__global__ __launch_bounds__(128) void k_feat(const ushort* __restrict__ hinb,
                                              const float* __restrict__ g,
                                              const float* __restrict__ be,
                                              const ushort* __restrict__ Bp2,
                                              const float* __restrict__ asrc,
                                              const float* __restrict__ adst,
                                              uint* __restrict__ hW8,
                                              float* __restrict__ esrc,
                                              float* __restrict__ edst) {
    __shared__ ushort hbf[2][16 * PADH];
    int t = threadIdx.x, w = t >> 6, l = t & 63;
    int m = l & 15, q = l >> 4;
    int n0w = blockIdx.x * 32 + w * 16;
    bool active = (n0w < NN);
    int nb = active ? n0w : 0;

    const float4* g4  = reinterpret_cast<const float4*>(g);
    const float4* be4 = reinterpret_cast<const float4*>(be);
    // 4 iters: slot s = l + 64i -> node = s>>4 (16 lanes/node), c8 = s&15 (cols 8*c8..)
    #pragma unroll
    for (int i = 0; i < 4; ++i) {
        int s = l + 64 * i;
        int node = s >> 4, c8 = s & 15;
        uint4 v = *reinterpret_cast<const uint4*>(hinb + (size_t)(nb + node) * HID + c8 * 8);
        float f[8] = { b2f_lo(v.x), b2f_hi(v.x), b2f_lo(v.y), b2f_hi(v.y),
                       b2f_lo(v.z), b2f_hi(v.z), b2f_lo(v.w), b2f_hi(v.w) };
        float s1 = 0.f, s2 = 0.f;
        #pragma unroll
        for (int j = 0; j < 8; ++j) { s1 += f[j]; s2 = fmaf(f[j], f[j], s2); }
        #pragma unroll
        for (int mk = 1; mk < 16; mk <<= 1) {
            s1 += __shfl_xor(s1, mk, 16);
            s2 += __shfl_xor(s2, mk, 16);
        }
        float mu = s1 * (1.f / 128.f);
        float var = s2 * (1.f / 128.f) - mu * mu;
        float rs = rsqrtf(var + 1e-5f);
        float4 gg0 = g4[c8 * 2], gg1 = g4[c8 * 2 + 1];
        float4 bb0 = be4[c8 * 2], bb1 = be4[c8 * 2 + 1];
        float gv[8] = {gg0.x, gg0.y, gg0.z, gg0.w, gg1.x, gg1.y, gg1.z, gg1.w};
        float bv[8] = {bb0.x, bb0.y, bb0.z, bb0.w, bb1.x, bb1.y, bb1.z, bb1.w};
        ushort4 p0, p1;
        p0.x = f2b(gelu_f((f[0] - mu) * rs * gv[0] + bv[0]));
        p0.y = f2b(gelu_f((f[1] - mu) * rs * gv[1] + bv[1]));
        p0.z = f2b(gelu_f((f[2] - mu) * rs * gv[2] + bv[2]));
        p0.w = f2b(gelu_f((f[3] - mu) * rs * gv[3] + bv[3]));
        p1.x = f2b(gelu_f((f[4] - mu) * rs * gv[4] + bv[4]));
        p1.y = f2b(gelu_f((f[5] - mu) * rs * gv[5] + bv[5]));
        p1.z = f2b(gelu_f((f[6] - mu) * rs * gv[6] + bv[6]));
        p1.w = f2b(gelu_f((f[7] - mu) * rs * gv[7] + bv[7]));
        *reinterpret_cast<ushort4*>(&hbf[w][node * PADH + c8 * 8])     = p0;
        *reinterpret_cast<ushort4*>(&hbf[w][node * PADH + c8 * 8 + 4]) = p1;
    }
    __syncthreads();

    const short8* B2 = reinterpret_cast<const short8*>(Bp2);
    floatx4 acc2[8];
    #pragma unroll
    for (int T = 0; T < 8; ++T) acc2[T] = (floatx4){0.f, 0.f, 0.f, 0.f};
    #pragma unroll
    for (int s = 0; s < 4; ++s) {
        short8 a = *reinterpret_cast<const short8*>(&hbf[w][m * PADH + s * 32 + q * 8]);
        #pragma unroll
        for (int T = 0; T < 8; ++T) {
            short8 b = B2[(T * 4 + s) * 64 + l];
            acc2[T] = __builtin_amdgcn_mfma_f32_16x16x32_bf16(a, b, acc2[T], 0, 0, 0);
        }
    }

    __syncthreads();
    #pragma unroll
    for (int j = 0; j < 4; ++j)
        #pragma unroll
        for (int T = 0; T < 8; ++T)
            hbf[w][(q * 4 + j) * PADH + T * 16 + m] = f2b(acc2[T][j]);
    __syncthreads();
    pack_store_fp8(hbf[w], l, n0w, active, hW8);

    float as_[8], ad_[8];
    #pragma unroll
    for (int T = 0; T < 8; ++T) {
        int c = T * 16 + m;
        as_[T] = asrc[c]; ad_[T] = adst[c];
    }
    #pragma unroll
    for (int j = 0; j < 4; ++j) {
        #pragma unroll
        for (int h = 0; h < 4; ++h) {
            float v1 = fmaf(acc2[2 * h][j], as_[2 * h], acc2[2 * h + 1][j] * as_[2 * h + 1]);
            float v2 = fmaf(acc2[2 * h][j], ad_[2 * h], acc2[2 * h + 1][j] * ad_[2 * h + 1]);
            #pragma unroll
            for (int mk = 1; mk < 16; mk <<= 1) {
                v1 += __shfl_xor(v1, mk, 64);
                v2 += __shfl_xor(v2, mk, 64);
            }
            if (m == 0 && active) {
                esrc[(n0w + q * 4 + j) * 4 + h] = v1;
                edst[(n0w + q * 4 + j) * 4 + h] = v2;
            }
        }
    }
}

// ------- GAT aggregate v9: one wave per node, barrier/LDS-free, bf16 output -------
// 64 lanes = 4 edge slots x 16 col groups (uint2 = 8 fp8 cols). 2-wide pipeline:
// body processes batches it,it+1 (8 edges), prefetches rows it+2,it+3 + idx it+4,it+5.

__global__ __launch_bounds__(256) void k_gat(const uint* __restrict__ hW8,
                                             const float* __restrict__ esrc,
                                             const float* __restrict__ edst,
                                             const int* __restrict__ off,
                                             const int* __restrict__ csr,
                                             const float* __restrict__ bg,
                                             ushort* __restrict__ outb) {
    int t = threadIdx.x;
    int wv = t >> 6, l = t & 63;
    int slot = l >> 4;
    int q    = l & 15;
    int hq   = q >> 2;
    int n = blockIdx.x * 4 + wv;       // grid = NN/4 exactly
    int o0 = off[n], o1 = off[n + 1];
    float ednh = edst[n * 4 + hq];
    const uint2* hw2 = reinterpret_cast<const uint2*>(hW8);
    floatx2 a01 = {0.f, 0.f}, a23 = {0.f, 0.f}, a45 = {0.f, 0.f}, a67 = {0.f, 0.f};
    float dsum = 0.f;
    int nIter = (o1 - o0 + 7) >> 3;    // 8 edges per body (2 batches of 4)
    int e = o0 + slot;

    // prologue (csr padded with zeros past ETOT: no clamps)
    int srcA = csr[e];
    int srcB = csr[e + 4];
    int srcC = csr[e + 8];
    int srcD = csr[e + 12];
    float esA = esrc[srcA * 4 + hq];
    float esB = esrc[srcB * 4 + hq];
    uint2 rA = hw2[(size_t)srcA * 16 + q];
    uint2 rB = hw2[(size_t)srcB * 16 + q];

    for (int it = 0; it < nIter; ++it) {
        uint2 rC = hw2[(size_t)srcC * 16 + q];
        uint2 rD = hw2[(size_t)srcD * 16 + q];
        float esC = esrc[srcC * 4 + hq];
        float esD = esrc[srcD * 4 + hq];
        int srcE = csr[e + 16];
        int srcF = csr[e + 20];
        float ea = esA + ednh; ea = fmaxf(ea, 0.2f * ea);
        float eb = esB + ednh; eb = fmaxf(eb, 0.2f * eb);
        float wa = (e     < o1) ? __expf(ea) : 0.f;
        float wb = (e + 4 < o1) ? __expf(eb) : 0.f;
        floatx2 wa2 = {wa, wa}, wb2 = {wb, wb};
        a01 += wa2 * __builtin_amdgcn_cvt_pk_f32_fp8(rA.x, false);
        a23 += wa2 * __builtin_amdgcn_cvt_pk_f32_fp8(rA.x, true);
        a45 += wa2 * __builtin_amdgcn_cvt_pk_f32_fp8(rA.y, false);
        a67 += wa2 * __builtin_amdgcn_cvt_pk_f32_fp8(rA.y, true);
        a01 += wb2 * __builtin_amdgcn_cvt_pk_f32_fp8(rB.x, false);
        a23 += wb2 * __builtin_amdgcn_cvt_pk_f32_fp8(rB.x, true);
        a45 += wb2 * __builtin_amdgcn_cvt_pk_f32_fp8(rB.y, false);
        a67 += wb2 * __builtin_amdgcn_cvt_pk_f32_fp8(rB.y, true);
        dsum += wa + wb;
        e += 8;
        rA = rC; rB = rD;
        esA = esC; esB = esD;
        srcC = srcE; srcD = srcF;
    }
    float acc[8] = {a01[0], a01[1], a23[0], a23[1], a45[0], a45[1], a67[0], a67[1]};
    #pragma unroll
    for (int mk = 16; mk <= 32; mk <<= 1) {
        #pragma unroll
        for (int j = 0; j < 8; ++j) acc[j] += __shfl_xor(acc[j], mk, 64);
        dsum += __shfl_xor(dsum, mk, 64);
    }
    if (l < 16) {                       // slot-0 lanes hold all 16 col groups
        float inv = 1.0f / dsum;
        float v[8];
        #pragma unroll
        for (int j = 0; j < 8; ++j) v[j] = acc[j] * inv + bg[l * 8 + j];
        uint4 o;
        o.x = (uint)f2b(v[0]) | ((uint)f2b(v[1]) << 16);
        o.y = (uint)f2b(v[2]) | ((uint)f2b(v[3]) << 16);
        o.z = (uint)f2b(v[4]) | ((uint)f2b(v[5]) << 16);
        o.w = (uint)f2b(v[6]) | ((uint)f2b(v[7]) << 16);
        *reinterpret_cast<uint4*>(outb + (size_t)n * HID + l * 8) = o;
    }
}

// ------- output linear (bf16 input): 32 nodes/block, 4 nodes x 4 cols/thread -------

__global__ __launch_bounds__(128) void k_out(const ushort* __restrict__ hb,
                                             const float* __restrict__ w,
                                             const float* __restrict__ b,
                                             float* __restrict__ out) {
    __shared__ __align__(16) float hr[32 * 132];
    int t = threadIdx.x, n0 = blockIdx.x * 32;
    float4* hr4 = reinterpret_cast<float4*>(hr);
    #pragma unroll
    for (int i = 0; i < 4; ++i) {
        int s = t + 128 * i;           // 512 slots: node = s>>4, c8 = s&15
        int node = s >> 4, c8 = s & 15;
        uint4 v = *reinterpret_cast<const uint4*>(hb + (size_t)(n0 + node) * HID + c8 * 8);
        float4 lo = { b2f_lo(v.x), b2f_hi(v.x), b2f_lo(v.y), b2f_hi(v.y) };
        float4 hi = { b2f_lo(v.z), b2f_hi(v.z), b2f_lo(v.w), b2f_hi(v.w) };
        hr4[node * 33 + c8 * 2]     = lo;
        hr4[node * 33 + c8 * 2 + 1] = hi;
    }
    __syncthreads();
    int cg = t & 15, ng = t >> 4;
    const float4* w4 = reinterpret_cast<const float4*>(w);
    float4 bb = reinterpret_cast<const float4*>(b)[cg];
    float4 acc[4] = {bb, bb, bb, bb};
    for (int k4 = 0; k4 < 32; ++k4) {
        float4 w0 = w4[(k4 * 4 + 0) * 16 + cg];
        float4 w1 = w4[(k4 * 4 + 1) * 16 + cg];
        float4 w2 = w4[(k4 * 4 + 2) * 16 + cg];
        float4 w3 = w4[(k4 * 4 + 3) * 16 + cg];
        #pragma unroll
        for (int r = 0; r < 4; ++r) {
            float4 hv = hr4[(ng * 4 + r) * 33 + k4];
            acc[r].x = fmaf(hv.x, w0.x, fmaf(hv.y, w1.x, fmaf(hv.z, w2.x, fmaf(hv.w, w3.x, acc[r].x))));
            acc[r].y = fmaf(hv.x, w0.y, fmaf(hv.y, w1.y, fmaf(hv.z, w2.y, fmaf(hv.w, w3.y, acc[r].y))));
            acc[r].z = fmaf(hv.x, w0.z, fmaf(hv.y, w1.z, fmaf(hv.z, w2.z, fmaf(hv.w, w3.z, acc[r].z))));
            acc[r].w = fmaf(hv.x, w0.w, fmaf(hv.y, w1.w, fmaf(hv.z, w2.w, fmaf(hv.w, w3.w, acc[r].w))));
        }
    }
    float4* o4 = reinterpret_cast<float4*>(out) + (size_t)n0 * 16;
    #pragma unroll
    for (int r = 0; r < 4; ++r) {
        if (n0 + ng * 4 + r < NN)
            o4[(ng * 4 + r) * 16 + cg] = acc[r];
    }
}

extern "C" void kernel_launch(void* const* d_in, const int* in_sizes, int n_in,
                              void* d_out, int out_size, void* d_ws, size_t ws_size,
                              hipStream_t stream) {
    const float* x    = (const float*)d_in[0];
    const int*   ei   = (const int*)  d_in[1];
    const float* w_in = (const float*)d_in[2];
    const float* b_in = (const float*)d_in[3];
    const float* g1   = (const float*)d_in[4];
    const float* be1  = (const float*)d_in[5];
    const float* W1   = (const float*)d_in[6];
    const float* as1  = (const float*)d_in[7];
    const float* ad1  = (const float*)d_in[8];
    const float* bg1  = (const float*)d_in[9];
    const float* g2   = (const float*)d_in[10];
    const float* be2  = (const float*)d_in[11];
    const float* W2   = (const float*)d_in[12];
    const float* as2  = (const float*)d_in[13];
    const float* ad2  = (const float*)d_in[14];
    const float* bg2  = (const float*)d_in[15];
    const float* w_o  = (const float*)d_in[16];
    const float* b_o  = (const float*)d_in[17];
    float* out = (float*)d_out;

    char* p = (char*)d_ws;
    auto take = [&](size_t bytes) {
        void* r = p;
        p += (bytes + 255) & ~(size_t)255;
        return r;
    };
    ushort* gout  = (ushort*)take((size_t)(NN + 32) * HID * 2);  // bf16 (+pad rows for k_out/k_feat overread)
    ushort* h2    = (ushort*)take((size_t)(NN + 32) * HID * 2);  // bf16
    uint*   hW8   = (uint*)take((size_t)NN * HID);               // fp8 gather table
    float*  esrc  = (float*)take((size_t)NN * 4 * 4);
    float*  edst  = (float*)take((size_t)NN * 4 * 4);
    int*    off   = (int*)take((size_t)(NN + 1) * 4);
    int*    csr   = (int*)take((size_t)(ETOT + 64) * 4);         // +64 zeroed pad
    int*    tmp   = (int*)take((size_t)NBK * CAP * 4);
    int*    bcur  = (int*)take((size_t)NBK * 4);
    ushort* Bp1   = (ushort*)take((size_t)1024 * 16);
    ushort* BpW1  = (ushort*)take((size_t)2048 * 16);
    ushort* BpW2  = (ushort*)take((size_t)2048 * 16);

    k_packall   <<<20, 256, 0, stream>>>(w_in, W1, W2, Bp1, BpW1, BpW2, bcur, csr);
    k_bucket    <<<BBLK, 1024, 0, stream>>>(ei, bcur, tmp);
    k_bucket2csr<<<NBK, 512, 0, stream>>>(tmp, bcur, off, csr);

    int gfeat = (NN + 31) / 32;
    k_infeat<<<gfeat, 128, 0, stream>>>(x, Bp1, b_in, g1, be1, BpW1, as1, ad1, hW8, esrc, edst);
    k_gat   <<<NN / 4, 256, 0, stream>>>(hW8, esrc, edst, off, csr, bg1, gout);
    k_feat  <<<gfeat, 128, 0, stream>>>(gout, g2, be2, BpW2, as2, ad2, hW8, esrc, edst);
    k_gat   <<<NN / 4, 256, 0, stream>>>(hW8, esrc, edst, off, csr, bg2, h2);
    k_out   <<<(NN + 31) / 32, 128, 0, stream>>>(h2, w_o, b_o, out);
}